// Round 2
// baseline (6479.773 us; speedup 1.0000x reference)
//
#include <hip/hip_runtime.h>
#include <hip/hip_bf16.h>

typedef unsigned short u16;
typedef unsigned int u32;
typedef __attribute__((ext_vector_type(4))) float f32x4;
typedef __attribute__((ext_vector_type(8))) __bf16 bf16x8;

__device__ __forceinline__ u16 f2bf(float f) {
    u32 x = __float_as_uint(f);
    u32 r = x + 0x7fffu + ((x >> 16) & 1u);   // round-to-nearest-even
    return (u16)(r >> 16);
}
__device__ __forceinline__ float bf2f(u16 u) {
    return __uint_as_float(((u32)u) << 16);
}

// -------------------------------------------------------------------------
// Weight prep: 17 matrices [128x128] transposed to bf16  Wt[c][k] = W[k][c]
// layout per layer l (base l*8): 0 Wm_vf_top, 1 Wm_vf_bot, 2 Wm_fv_top,
// 3 Wm_fv_bot, 4 Wc_vf_top, 5 Wc_vf_bot, 6 Wc_fv_top, 7 Wc_fv_bot; 16 = Wt.
// -------------------------------------------------------------------------
__global__ __launch_bounds__(256) void prep_w(
    const float* __restrict__ Wm_vf, const float* __restrict__ Wc_vf,
    const float* __restrict__ Wm_fv, const float* __restrict__ Wc_fv,
    const float* __restrict__ Wtr, u16* __restrict__ dst)
{
    int i = blockIdx.x * 256 + threadIdx.x;
    if (i >= 17 * 16384) return;
    int m = i >> 14;
    int r = i & 16383;
    int c = r >> 7;
    int k = r & 127;
    const float* p;
    if (m == 16) {
        p = Wtr;
    } else {
        int l = m >> 3, j = m & 7;
        const float* base = (j < 2) ? Wm_vf : (j < 4) ? Wm_fv : (j < 6) ? Wc_vf : Wc_fv;
        p = base + l * 32768 + (j & 1) * 16384;
    }
    dst[m * 16384 + c * 128 + k] = f2bf(p[k * 128 + c]);
}

// -------------------------------------------------------------------------
// GEMM: Y[N,128] = (RES? res +) maybe_relu( X1@W1 (+ X2@W2) + bias )
// W given transposed bf16 [c][k]. 64 rows/block, 256 thr (4 waves),
// wave w -> rows w*16..w*16+15, all 128 cols (8 col-tiles).
// -------------------------------------------------------------------------
template <bool TWO, bool RELU, bool RES, bool OBF16>
__global__ __launch_bounds__(256) void gemm_k(
    const float* __restrict__ X1, const float* __restrict__ X2,
    const u16* __restrict__ W1, const u16* __restrict__ W2,
    const float* __restrict__ bias, const float* __restrict__ res,
    float* __restrict__ Yf, u16* __restrict__ Yb, int N)
{
    __shared__ __align__(16) u16 Xs[64 * 136];
    __shared__ __align__(16) u16 Ws[128 * 136];
    const int tid = threadIdx.x;
    const int lane = tid & 63;
    const int wv = tid >> 6;
    const int r0 = blockIdx.x * 64;

    f32x4 acc[8];
#pragma unroll
    for (int i = 0; i < 8; i++) acc[i] = (f32x4)0.f;

#pragma unroll
    for (int p = 0; p < (TWO ? 2 : 1); ++p) {
        const float* __restrict__ X = (TWO && p) ? X2 : X1;
        const u16* __restrict__ W = (TWO && p) ? W2 : W1;
        if (p) __syncthreads();   // let all waves finish K-loop before restage
        // stage X tile (f32 -> bf16), rows padded to 136
#pragma unroll
        for (int j = 0; j < 8; j++) {
            int q = j * 256 + tid;
            int row = q >> 5;
            int col = (q & 31) * 4;
            float4 v = make_float4(0.f, 0.f, 0.f, 0.f);
            int gr = r0 + row;
            if (gr < N) v = *(const float4*)&X[(size_t)gr * 128 + col];
            ushort4 h;
            h.x = f2bf(v.x); h.y = f2bf(v.y); h.z = f2bf(v.z); h.w = f2bf(v.w);
            *(ushort4*)&Xs[row * 136 + col] = h;
        }
        // stage W (bf16, already transposed [c][k])
#pragma unroll
        for (int j = 0; j < 8; j++) {
            int q = j * 256 + tid;
            int c = q >> 4;
            int k = (q & 15) * 8;
            uint4 w = *(const uint4*)&W[c * 128 + k];
            *(uint4*)&Ws[c * 136 + k] = w;
        }
        __syncthreads();
#pragma unroll
        for (int ks = 0; ks < 4; ks++) {
            bf16x8 a = *(const bf16x8*)&Xs[(wv * 16 + (lane & 15)) * 136 + ks * 32 + (lane >> 4) * 8];
#pragma unroll
            for (int ct = 0; ct < 8; ct++) {
                bf16x8 b = *(const bf16x8*)&Ws[(ct * 16 + (lane & 15)) * 136 + ks * 32 + (lane >> 4) * 8];
                acc[ct] = __builtin_amdgcn_mfma_f32_16x16x32_bf16(a, b, acc[ct], 0, 0, 0);
            }
        }
    }
    // epilogue: D mapping row=(lane>>4)*4+r, col=ct*16+(lane&15)
#pragma unroll
    for (int ct = 0; ct < 8; ct++) {
        int col = ct * 16 + (lane & 15);
        float bv = bias ? bias[col] : 0.f;
#pragma unroll
        for (int r = 0; r < 4; r++) {
            int row = wv * 16 + (lane >> 4) * 4 + r;
            int gr = r0 + row;
            if (gr < N) {
                float v = acc[ct][r] + bv;
                if (RELU) v = fmaxf(v, 0.f);
                if (RES) v += res[(size_t)gr * 128 + col];
                if (OBF16) Yb[(size_t)gr * 128 + col] = f2bf(v);
                else       Yf[(size_t)gr * 128 + col] = v;
            }
        }
    }
}

// -------------------------------------------------------------------------
// Edge scatter: agg[idxA[e]] += relu(HA[idxA[e]] + HB[idxB[e]] + bias)
// 32 threads per edge (4 cols each), 8 edges per 256-thr block.
// -------------------------------------------------------------------------
__global__ __launch_bounds__(256) void edge_scatter(
    const u16* __restrict__ HA, const u16* __restrict__ HB,
    const int* __restrict__ idxA, const int* __restrict__ idxB,
    const float* __restrict__ bias, float* __restrict__ agg, int E)
{
    int tid = threadIdx.x;
    int e = blockIdx.x * 8 + (tid >> 5);
    if (e >= E) return;
    int d0 = (tid & 31) * 4;
    int ia = idxA[e];
    int ib = idxB[e];
    ushort4 ha = *(const ushort4*)&HA[(size_t)ia * 128 + d0];
    ushort4 hb = *(const ushort4*)&HB[(size_t)ib * 128 + d0];
    float4 bv = *(const float4*)&bias[d0];
    float v0 = fmaxf(bf2f(ha.x) + bf2f(hb.x) + bv.x, 0.f);
    float v1 = fmaxf(bf2f(ha.y) + bf2f(hb.y) + bv.y, 0.f);
    float v2 = fmaxf(bf2f(ha.z) + bf2f(hb.z) + bv.z, 0.f);
    float v3 = fmaxf(bf2f(ha.w) + bf2f(hb.w) + bv.w, 0.f);
    float* base = &agg[(size_t)ia * 128 + d0];
    unsafeAtomicAdd(base + 0, v0);
    unsafeAtomicAdd(base + 1, v1);
    unsafeAtomicAdd(base + 2, v2);
    unsafeAtomicAdd(base + 3, v3);
}

// -------------------------------------------------------------------------
// gate[f] = factors[f] . Wg + bg   (one wave per factor, 4 factors/block)
// -------------------------------------------------------------------------
__global__ __launch_bounds__(256) void gate_k(
    const float* __restrict__ F, const float* __restrict__ Wg,
    const float* __restrict__ bg, float* __restrict__ gate, int NF)
{
    int lane = threadIdx.x & 63;
    int f = blockIdx.x * 4 + (threadIdx.x >> 6);
    if (f >= NF) return;
    float p = F[(size_t)f * 128 + lane] * Wg[lane]
            + F[(size_t)f * 128 + 64 + lane] * Wg[64 + lane];
#pragma unroll
    for (int off = 32; off; off >>= 1) p += __shfl_down(p, off);
    if (lane == 0) gate[f] = p + bg[0];
}

// -------------------------------------------------------------------------
// Per-group segment softmax over gate, weighted sum of T rows -> g_att,
// then fused final: out = relu(g_att @ Wl[:128] + bl).  64 blocks x 128 thr.
// -------------------------------------------------------------------------
__global__ __launch_bounds__(128) void gatt_k(
    const float* __restrict__ gate, const float* __restrict__ T,
    const int* __restrict__ batch, const float* __restrict__ Wl,
    const float* __restrict__ bl, float* __restrict__ g_out, int NF)
{
    int g = blockIdx.x, tid = threadIdx.x;
    // binary search group bounds in sorted batch
    int lo = 0, hi = NF;
    while (lo < hi) { int mid = (lo + hi) >> 1; if (batch[mid] < g) lo = mid + 1; else hi = mid; }
    int start = lo;
    lo = start; hi = NF;
    while (lo < hi) { int mid = (lo + hi) >> 1; if (batch[mid] < g + 1) lo = mid + 1; else hi = mid; }
    int end = lo;

    __shared__ float red[128];
    float m = -3.4e38f;
    for (int i = start + tid; i < end; i += 128) m = fmaxf(m, gate[i]);
    red[tid] = m; __syncthreads();
    for (int s = 64; s; s >>= 1) { if (tid < s) red[tid] = fmaxf(red[tid], red[tid + s]); __syncthreads(); }
    float mx = red[0]; __syncthreads();

    float ssum = 0.f;
    for (int i = start + tid; i < end; i += 128) ssum += __expf(gate[i] - mx);
    red[tid] = ssum; __syncthreads();
    for (int s = 64; s; s >>= 1) { if (tid < s) red[tid] += red[tid + s]; __syncthreads(); }
    float denom = red[0];

    float acc = 0.f;
    for (int i = start; i < end; i++) {
        float e = __expf(gate[i] - mx);
        acc += e * T[(size_t)i * 128 + tid];
    }
    acc = (end > start) ? acc / denom : 0.f;

    __shared__ float ga[128];
    ga[tid] = acc; __syncthreads();
    float o = bl[tid];
    for (int k = 0; k < 128; k++) o += ga[k] * Wl[k * 128 + tid];
    g_out[(size_t)g * 128 + tid] = fmaxf(o, 0.f);
}

// -------------------------------------------------------------------------
extern "C" void kernel_launch(void* const* d_in, const int* in_sizes, int n_in,
                              void* d_out, int out_size, void* d_ws, size_t ws_size,
                              hipStream_t stream)
{
    const int D = 128;
    const int NV = in_sizes[0] / D;
    const int NF = in_sizes[1] / D;
    const int E  = in_sizes[2] / 2;
    const int G  = out_size / D - NV - NF;

    const float* vars_in = (const float*)d_in[0];
    const float* facs_in = (const float*)d_in[1];
    const int*   eidx    = (const int*)d_in[2];
    const int*   e_src   = eidx;        // variable index per edge
    const int*   e_dst   = eidx + E;    // factor index per edge
    const int*   batch   = (const int*)d_in[4];
    const float* Wm_vf = (const float*)d_in[5],  *bm_vf = (const float*)d_in[6];
    const float* Wc_vf = (const float*)d_in[7],  *bc_vf = (const float*)d_in[8];
    const float* Wm_fv = (const float*)d_in[9],  *bm_fv = (const float*)d_in[10];
    const float* Wc_fv = (const float*)d_in[11], *bc_fv = (const float*)d_in[12];
    const float* Wg  = (const float*)d_in[13], *bg = (const float*)d_in[14];
    const float* Wtr = (const float*)d_in[15], *bt = (const float*)d_in[16];
    const float* Wl  = (const float*)d_in[17], *bl = (const float*)d_in[18];

    // workspace layout (AGG_F / AGG_V lifetimes are disjoint -> shared region)
    char* ws = (char*)d_ws;
    u16*   WB    = (u16*)ws;                                 // 17*16384 bf16 (<1 MB)
    u16*   BUFA  = (u16*)(ws + (1 << 20));                   // 25.6 MB bf16
    u16*   BUFB  = (u16*)(ws + (1 << 20) + 25600000);        // 25.6 MB bf16
    float* AGG   = (float*)(ws + 52248576);                  // 51.2 MB f32 (shared F/V)
    float* Tbuf  = (float*)BUFA;                             // 51.2 MB f32 (reuse A+B)
    float* gate  = AGG;                                      // reuse (dead after layers)

    float* out_v = (float*)d_out;
    float* out_f = out_v + (size_t)NV * D;
    float* out_g = out_f + (size_t)NF * D;

    prep_w<<<(17 * 16384 + 255) / 256, 256, 0, stream>>>(Wm_vf, Wc_vf, Wm_fv, Wc_fv, Wtr, WB);
    hipMemcpyAsync(out_v, vars_in, (size_t)NV * D * 4, hipMemcpyDeviceToDevice, stream);
    hipMemcpyAsync(out_f, facs_in, (size_t)NF * D * 4, hipMemcpyDeviceToDevice, stream);

    const int GBv = (NV + 63) / 64;
    const int GBf = (NF + 63) / 64;

    for (int l = 0; l < 2; l++) {
        u16* wb = WB + l * 8 * 16384;
        // var->factor halves: Fh = F@Wm_vf_top -> BUFA ; Vh = V@Wm_vf_bot -> BUFB
        gemm_k<false, false, false, true><<<GBf, 256, 0, stream>>>(
            out_f, nullptr, wb + 0 * 16384, nullptr, nullptr, nullptr, nullptr, BUFA, NF);
        gemm_k<false, false, false, true><<<GBv, 256, 0, stream>>>(
            out_v, nullptr, wb + 1 * 16384, nullptr, nullptr, nullptr, nullptr, BUFB, NV);
        hipMemsetAsync(AGG, 0, (size_t)NF * D * 4, stream);
        edge_scatter<<<(E + 7) / 8, 256, 0, stream>>>(
            BUFA, BUFB, e_dst, e_src, bm_vf + l * D, AGG, E);
        // factor->var halves (uses OLD state): Vh = V@Wm_fv_top -> BUFA ; Fh = F@Wm_fv_bot -> BUFB
        gemm_k<false, false, false, true><<<GBv, 256, 0, stream>>>(
            out_v, nullptr, wb + 2 * 16384, nullptr, nullptr, nullptr, nullptr, BUFA, NV);
        gemm_k<false, false, false, true><<<GBf, 256, 0, stream>>>(
            out_f, nullptr, wb + 3 * 16384, nullptr, nullptr, nullptr, nullptr, BUFB, NF);
        // combine factors in place: F = relu(F@Wc_top + AGG@Wc_bot + bc)
        gemm_k<true, true, false, false><<<GBf, 256, 0, stream>>>(
            out_f, AGG, wb + 4 * 16384, wb + 5 * 16384, bc_vf + l * D, nullptr, out_f, nullptr, NF);
        hipMemsetAsync(AGG, 0, (size_t)NV * D * 4, stream);
        edge_scatter<<<(E + 7) / 8, 256, 0, stream>>>(
            BUFA, BUFB, e_src, e_dst, bm_fv + l * D, AGG, E);
        // combine variables in place with residual: V = V + relu(V@Wc_top + AGG@Wc_bot + bc)
        gemm_k<true, true, true, false><<<GBv, 256, 0, stream>>>(
            out_v, AGG, wb + 6 * 16384, wb + 7 * 16384, bc_fv + l * D, out_v, out_v, nullptr, NV);
    }

    // global node
    gemm_k<false, false, false, false><<<GBf, 256, 0, stream>>>(
        out_f, nullptr, WB + 16 * 16384, nullptr, bt, nullptr, Tbuf, nullptr, NF);
    gate_k<<<(NF + 3) / 4, 256, 0, stream>>>(out_f, Wg, bg, gate, NF);
    gatt_k<<<G, 128, 0, stream>>>(gate, Tbuf, batch, Wl, bl, out_g, NF);
}

// Round 3
// 1177.639 us; speedup vs baseline: 5.5023x; 5.5023x over previous
//
#include <hip/hip_runtime.h>
#include <hip/hip_bf16.h>

typedef unsigned short u16;
typedef unsigned int u32;
typedef __attribute__((ext_vector_type(4))) float f32x4;
typedef __attribute__((ext_vector_type(8))) __bf16 bf16x8;

__device__ __forceinline__ u16 f2bf(float f) {
    u32 x = __float_as_uint(f);
    u32 r = x + 0x7fffu + ((x >> 16) & 1u);   // round-to-nearest-even
    return (u16)(r >> 16);
}
__device__ __forceinline__ float bf2f(u16 u) {
    return __uint_as_float(((u32)u) << 16);
}

// -------------------------------------------------------------------------
// Weight prep: 17 matrices [128x128] transposed to bf16  Wt[c][k] = W[k][c]
// per layer l (base l*8): 0 Wm_vf_top, 1 Wm_vf_bot, 2 Wm_fv_top, 3 Wm_fv_bot,
// 4 Wc_vf_top, 5 Wc_vf_bot, 6 Wc_fv_top, 7 Wc_fv_bot; 16 = Wt.
// -------------------------------------------------------------------------
__global__ __launch_bounds__(256) void prep_w(
    const float* __restrict__ Wm_vf, const float* __restrict__ Wc_vf,
    const float* __restrict__ Wm_fv, const float* __restrict__ Wc_fv,
    const float* __restrict__ Wtr, u16* __restrict__ dst)
{
    int i = blockIdx.x * 256 + threadIdx.x;
    if (i >= 17 * 16384) return;
    int m = i >> 14;
    int r = i & 16383;
    int c = r >> 7;
    int k = r & 127;
    const float* p;
    if (m == 16) {
        p = Wtr;
    } else {
        int l = m >> 3, j = m & 7;
        const float* base = (j < 2) ? Wm_vf : (j < 4) ? Wm_fv : (j < 6) ? Wc_vf : Wc_fv;
        p = base + l * 32768 + (j & 1) * 16384;
    }
    dst[m * 16384 + c * 128 + k] = f2bf(p[k * 128 + c]);
}

// -------------------------------------------------------------------------
// CSR build: histogram -> exclusive scan (3 phase) -> fill
// -------------------------------------------------------------------------
__global__ __launch_bounds__(256) void hist_k(
    const int* __restrict__ es, const int* __restrict__ ed,
    int* __restrict__ cntV, int* __restrict__ cntF, int E)
{
    int e = blockIdx.x * 256 + threadIdx.x;
    if (e >= E) return;
    atomicAdd(&cntV[es[e]], 1);
    atomicAdd(&cntF[ed[e]], 1);
}

// block scans 1024 elems (256 thr x 4), writes exclusive partials + block sum
__global__ __launch_bounds__(256) void scan1_k(
    const int* __restrict__ cnt, int* __restrict__ rs, int* __restrict__ bsum, int N)
{
    __shared__ int sd[256];
    int t = threadIdx.x;
    int b0 = blockIdx.x * 1024;
    int v[4]; int s = 0;
#pragma unroll
    for (int j = 0; j < 4; j++) { int i = b0 + t * 4 + j; v[j] = (i < N) ? cnt[i] : 0; s += v[j]; }
    sd[t] = s; __syncthreads();
    for (int off = 1; off < 256; off <<= 1) {
        int x = (t >= off) ? sd[t - off] : 0;
        __syncthreads();
        sd[t] += x;
        __syncthreads();
    }
    int excl = sd[t] - s;
    if (t == 255) bsum[blockIdx.x] = sd[255];
    int run = excl;
#pragma unroll
    for (int j = 0; j < 4; j++) { int i = b0 + t * 4 + j; if (i < N) rs[i] = run; run += v[j]; }
}

__global__ __launch_bounds__(256) void scan2_k(int* __restrict__ bsum, int NB)
{
    __shared__ int sd[256];
    int t = threadIdx.x;
    int s = (t < NB) ? bsum[t] : 0;
    sd[t] = s; __syncthreads();
    for (int off = 1; off < 256; off <<= 1) {
        int x = (t >= off) ? sd[t - off] : 0;
        __syncthreads();
        sd[t] += x;
        __syncthreads();
    }
    if (t < NB) bsum[t] = sd[t] - s;   // exclusive
}

__global__ __launch_bounds__(256) void scan3_k(
    int* __restrict__ rs, const int* __restrict__ bsum, int N, int E)
{
    int i = blockIdx.x * 256 + threadIdx.x;
    if (i < N) rs[i] += bsum[i >> 10];
    else if (i == N) rs[N] = E;
}

__global__ __launch_bounds__(256) void fill_k(
    const int* __restrict__ es, const int* __restrict__ ed,
    const int* __restrict__ rsF, const int* __restrict__ rsV,
    int* __restrict__ curF, int* __restrict__ curV,
    int* __restrict__ elF, int* __restrict__ elV, int E)
{
    int e = blockIdx.x * 256 + threadIdx.x;
    if (e >= E) return;
    int v = es[e], f = ed[e];
    int pF = rsF[f] + atomicAdd(&curF[f], 1);
    elF[pF] = v;
    int pV = rsV[v] + atomicAdd(&curV[v], 1);
    elV[pV] = f;
}

// -------------------------------------------------------------------------
// CSR aggregation: for each row w (one wave):
//   AGG[w] = sum_{o in adj(w)} relu(OWN[w] + OTH[o] + bias)   (written bf16,
// in place over OWN — safe: gathers touch only OTH). Zero-degree -> zeros.
// -------------------------------------------------------------------------
__global__ __launch_bounds__(256) void aggregate_k(
    u16* __restrict__ OWN, const u16* __restrict__ OTH,
    const int* __restrict__ rs, const int* __restrict__ el,
    const float* __restrict__ bias, int N)
{
    int row = blockIdx.x * 4 + (threadIdx.x >> 6);
    if (row >= N) return;
    int lane = threadIdx.x & 63;
    int start = rs[row], end = rs[row + 1];
    ushort2 h = *(const ushort2*)&OWN[(size_t)row * 128 + lane * 2];
    float2 bv = *(const float2*)&bias[lane * 2];
    float c0 = bf2f(h.x) + bv.x;
    float c1 = bf2f(h.y) + bv.y;
    float a0 = 0.f, a1 = 0.f;
    for (int p0 = start; p0 < end; p0 += 64) {
        int n = end - p0; if (n > 64) n = 64;
        int myidx = (lane < n) ? el[p0 + lane] : 0;
        for (int j = 0; j < n; j++) {
            int o = __shfl(myidx, j);
            ushort2 hb = *(const ushort2*)&OTH[(size_t)o * 128 + lane * 2];
            a0 += fmaxf(c0 + bf2f(hb.x), 0.f);
            a1 += fmaxf(c1 + bf2f(hb.y), 0.f);
        }
    }
    ushort2 r; r.x = f2bf(a0); r.y = f2bf(a1);
    *(ushort2*)&OWN[(size_t)row * 128 + lane * 2] = r;
}

// -------------------------------------------------------------------------
// GEMM: Y[N,128] = (RES? res +) maybe_relu( X1@W1 (+ X2@W2) + bias )
// X2 optionally bf16 (aggregate buffer). W transposed bf16 [c][k].
// 64 rows/block, 4 waves; wave w -> rows w*16.., 8 col-tiles.
// -------------------------------------------------------------------------
template <bool TWO, bool X2BF, bool RELU, bool RES, bool OBF16>
__global__ __launch_bounds__(256) void gemm_k(
    const float* __restrict__ X1, const void* __restrict__ X2,
    const u16* __restrict__ W1, const u16* __restrict__ W2,
    const float* __restrict__ bias, const float* __restrict__ res,
    float* __restrict__ Yf, u16* __restrict__ Yb, int N)
{
    __shared__ __align__(16) u16 Xs[64 * 136];
    __shared__ __align__(16) u16 Ws[128 * 136];
    const int tid = threadIdx.x;
    const int lane = tid & 63;
    const int wv = tid >> 6;
    const int r0 = blockIdx.x * 64;

    f32x4 acc[8];
#pragma unroll
    for (int i = 0; i < 8; i++) acc[i] = (f32x4)0.f;

#pragma unroll
    for (int p = 0; p < (TWO ? 2 : 1); ++p) {
        const u16* __restrict__ W = (TWO && p) ? W2 : W1;
        if (p) __syncthreads();
        if (TWO && p && X2BF) {
            const u16* Xb = (const u16*)X2;
#pragma unroll
            for (int j = 0; j < 4; j++) {
                int q = j * 256 + tid;
                int row = q >> 4;
                int col = (q & 15) * 8;
                uint4 v = make_uint4(0, 0, 0, 0);
                int gr = r0 + row;
                if (gr < N) v = *(const uint4*)&Xb[(size_t)gr * 128 + col];
                *(uint4*)&Xs[row * 136 + col] = v;
            }
        } else {
            const float* __restrict__ X = (TWO && p) ? (const float*)X2 : X1;
#pragma unroll
            for (int j = 0; j < 8; j++) {
                int q = j * 256 + tid;
                int row = q >> 5;
                int col = (q & 31) * 4;
                float4 v = make_float4(0.f, 0.f, 0.f, 0.f);
                int gr = r0 + row;
                if (gr < N) v = *(const float4*)&X[(size_t)gr * 128 + col];
                ushort4 h;
                h.x = f2bf(v.x); h.y = f2bf(v.y); h.z = f2bf(v.z); h.w = f2bf(v.w);
                *(ushort4*)&Xs[row * 136 + col] = h;
            }
        }
#pragma unroll
        for (int j = 0; j < 8; j++) {
            int q = j * 256 + tid;
            int c = q >> 4;
            int k = (q & 15) * 8;
            uint4 w = *(const uint4*)&W[c * 128 + k];
            *(uint4*)&Ws[c * 136 + k] = w;
        }
        __syncthreads();
#pragma unroll
        for (int ks = 0; ks < 4; ks++) {
            bf16x8 a = *(const bf16x8*)&Xs[(wv * 16 + (lane & 15)) * 136 + ks * 32 + (lane >> 4) * 8];
#pragma unroll
            for (int ct = 0; ct < 8; ct++) {
                bf16x8 b = *(const bf16x8*)&Ws[(ct * 16 + (lane & 15)) * 136 + ks * 32 + (lane >> 4) * 8];
                acc[ct] = __builtin_amdgcn_mfma_f32_16x16x32_bf16(a, b, acc[ct], 0, 0, 0);
            }
        }
    }
#pragma unroll
    for (int ct = 0; ct < 8; ct++) {
        int col = ct * 16 + (lane & 15);
        float bv = bias ? bias[col] : 0.f;
#pragma unroll
        for (int r = 0; r < 4; r++) {
            int row = wv * 16 + (lane >> 4) * 4 + r;
            int gr = r0 + row;
            if (gr < N) {
                float v = acc[ct][r] + bv;
                if (RELU) v = fmaxf(v, 0.f);
                if (RES) v += res[(size_t)gr * 128 + col];
                if (OBF16) Yb[(size_t)gr * 128 + col] = f2bf(v);
                else       Yf[(size_t)gr * 128 + col] = v;
            }
        }
    }
}

// -------------------------------------------------------------------------
// Dual GEMM: stage X once, Y1 = X@W1, Y2 = X@W2 (both bf16 out, no bias).
// -------------------------------------------------------------------------
__global__ __launch_bounds__(256) void gemm_dual(
    const float* __restrict__ X, const u16* __restrict__ W1, const u16* __restrict__ W2,
    u16* __restrict__ Y1, u16* __restrict__ Y2, int N)
{
    __shared__ __align__(16) u16 Xs[64 * 136];
    __shared__ __align__(16) u16 Ws[128 * 136];
    const int tid = threadIdx.x;
    const int lane = tid & 63;
    const int wv = tid >> 6;
    const int r0 = blockIdx.x * 64;

    f32x4 acc1[8], acc2[8];
#pragma unroll
    for (int i = 0; i < 8; i++) { acc1[i] = (f32x4)0.f; acc2[i] = (f32x4)0.f; }

    // stage X (f32 -> bf16)
#pragma unroll
    for (int j = 0; j < 8; j++) {
        int q = j * 256 + tid;
        int row = q >> 5;
        int col = (q & 31) * 4;
        float4 v = make_float4(0.f, 0.f, 0.f, 0.f);
        int gr = r0 + row;
        if (gr < N) v = *(const float4*)&X[(size_t)gr * 128 + col];
        ushort4 h;
        h.x = f2bf(v.x); h.y = f2bf(v.y); h.z = f2bf(v.z); h.w = f2bf(v.w);
        *(ushort4*)&Xs[row * 136 + col] = h;
    }
#pragma unroll
    for (int p = 0; p < 2; ++p) {
        const u16* __restrict__ W = p ? W2 : W1;
        if (p) __syncthreads();   // all waves done reading Ws from pass 0
#pragma unroll
        for (int j = 0; j < 8; j++) {
            int q = j * 256 + tid;
            int c = q >> 4;
            int k = (q & 15) * 8;
            uint4 w = *(const uint4*)&W[c * 128 + k];
            *(uint4*)&Ws[c * 136 + k] = w;
        }
        __syncthreads();
#pragma unroll
        for (int ks = 0; ks < 4; ks++) {
            bf16x8 a = *(const bf16x8*)&Xs[(wv * 16 + (lane & 15)) * 136 + ks * 32 + (lane >> 4) * 8];
#pragma unroll
            for (int ct = 0; ct < 8; ct++) {
                bf16x8 b = *(const bf16x8*)&Ws[(ct * 16 + (lane & 15)) * 136 + ks * 32 + (lane >> 4) * 8];
                if (p) acc2[ct] = __builtin_amdgcn_mfma_f32_16x16x32_bf16(a, b, acc2[ct], 0, 0, 0);
                else   acc1[ct] = __builtin_amdgcn_mfma_f32_16x16x32_bf16(a, b, acc1[ct], 0, 0, 0);
            }
        }
    }
#pragma unroll
    for (int ct = 0; ct < 8; ct++) {
        int col = ct * 16 + (lane & 15);
#pragma unroll
        for (int r = 0; r < 4; r++) {
            int row = wv * 16 + (lane >> 4) * 4 + r;
            int gr = r0 + row;
            if (gr < N) {
                Y1[(size_t)gr * 128 + col] = f2bf(acc1[ct][r]);
                Y2[(size_t)gr * 128 + col] = f2bf(acc2[ct][r]);
            }
        }
    }
}

// -------------------------------------------------------------------------
// gate[f] = factors[f] . Wg + bg
// -------------------------------------------------------------------------
__global__ __launch_bounds__(256) void gate_k(
    const float* __restrict__ F, const float* __restrict__ Wg,
    const float* __restrict__ bg, float* __restrict__ gate, int NF)
{
    int lane = threadIdx.x & 63;
    int f = blockIdx.x * 4 + (threadIdx.x >> 6);
    if (f >= NF) return;
    float p = F[(size_t)f * 128 + lane] * Wg[lane]
            + F[(size_t)f * 128 + 64 + lane] * Wg[64 + lane];
#pragma unroll
    for (int off = 32; off; off >>= 1) p += __shfl_down(p, off);
    if (lane == 0) gate[f] = p + bg[0];
}

// -------------------------------------------------------------------------
// Per-group max + exp-sum of gate (batch sorted). One block per group.
// -------------------------------------------------------------------------
__global__ __launch_bounds__(256) void gstats_k(
    const float* __restrict__ gate, const int* __restrict__ batch,
    float* __restrict__ mx, float* __restrict__ dn, int NF)
{
    int g = blockIdx.x, tid = threadIdx.x;
    int lo = 0, hi = NF;
    while (lo < hi) { int mid = (lo + hi) >> 1; if (batch[mid] < g) lo = mid + 1; else hi = mid; }
    int start = lo;
    lo = start; hi = NF;
    while (lo < hi) { int mid = (lo + hi) >> 1; if (batch[mid] < g + 1) lo = mid + 1; else hi = mid; }
    int end = lo;

    __shared__ float red[256];
    float m = -3.4e38f;
    for (int i = start + tid; i < end; i += 256) m = fmaxf(m, gate[i]);
    red[tid] = m; __syncthreads();
    for (int s = 128; s; s >>= 1) { if (tid < s) red[tid] = fmaxf(red[tid], red[tid + s]); __syncthreads(); }
    float mval = red[0]; __syncthreads();
    float s = 0.f;
    for (int i = start + tid; i < end; i += 256) s += __expf(gate[i] - mval);
    red[tid] = s; __syncthreads();
    for (int t = 128; t; t >>= 1) { if (tid < t) red[tid] += red[tid + t]; __syncthreads(); }
    if (tid == 0) { mx[g] = mval; dn[g] = red[0]; }
}

// -------------------------------------------------------------------------
// Segmented weighted sum: g_att[g] += sum_i attn[i] * T[i].  Chunks of 256
// sorted factors per block (128 thr = cols); atomic flush per segment edge.
// -------------------------------------------------------------------------
__global__ __launch_bounds__(128) void wsum_k(
    const float* __restrict__ gate, const float* __restrict__ T,
    const int* __restrict__ batch, const float* __restrict__ mx,
    const float* __restrict__ dn, float* __restrict__ g_att, int NF)
{
    int tid = threadIdx.x;
    int i0 = blockIdx.x * 256;
    if (i0 >= NF) return;
    int iend = i0 + 256; if (iend > NF) iend = NF;
    int curg = batch[i0];
    float acc = 0.f;
    for (int i = i0; i < iend; i++) {
        int g = batch[i];
        if (g != curg) {
            atomicAdd(&g_att[(size_t)curg * 128 + tid], acc);
            acc = 0.f; curg = g;
        }
        float w = __expf(gate[i] - mx[g]) / dn[g];
        acc += w * T[(size_t)i * 128 + tid];
    }
    atomicAdd(&g_att[(size_t)curg * 128 + tid], acc);
}

__global__ __launch_bounds__(128) void gfinal_k(
    const float* __restrict__ g_att, const float* __restrict__ Wl,
    const float* __restrict__ bl, float* __restrict__ out_g)
{
    int g = blockIdx.x, tid = threadIdx.x;
    __shared__ float ga[128];
    ga[tid] = g_att[(size_t)g * 128 + tid];
    __syncthreads();
    float o = bl[tid];
    for (int k = 0; k < 128; k++) o += ga[k] * Wl[k * 128 + tid];
    out_g[(size_t)g * 128 + tid] = fmaxf(o, 0.f);
}

// -------------------------------------------------------------------------
extern "C" void kernel_launch(void* const* d_in, const int* in_sizes, int n_in,
                              void* d_out, int out_size, void* d_ws, size_t ws_size,
                              hipStream_t stream)
{
    const int D = 128;
    const int NV = in_sizes[0] / D;
    const int NF = in_sizes[1] / D;
    const int E  = in_sizes[2] / 2;
    const int G  = out_size / D - NV - NF;

    const float* vars_in = (const float*)d_in[0];
    const float* facs_in = (const float*)d_in[1];
    const int*   eidx    = (const int*)d_in[2];
    const int*   e_src   = eidx;        // variable index per edge
    const int*   e_dst   = eidx + E;    // factor index per edge
    const int*   batch   = (const int*)d_in[4];
    const float* Wm_vf = (const float*)d_in[5],  *bm_vf = (const float*)d_in[6];
    const float* Wc_vf = (const float*)d_in[7],  *bc_vf = (const float*)d_in[8];
    const float* Wm_fv = (const float*)d_in[9],  *bm_fv = (const float*)d_in[10];
    const float* Wc_fv = (const float*)d_in[11], *bc_fv = (const float*)d_in[12];
    const float* Wg  = (const float*)d_in[13], *bg = (const float*)d_in[14];
    const float* Wtr = (const float*)d_in[15], *bt = (const float*)d_in[16];
    const float* Wl  = (const float*)d_in[17], *bl = (const float*)d_in[18];

    // workspace layout (~87 MB peak; round-2's 103 MB fit)
    char* ws = (char*)d_ws;
    size_t off = 0;
    u16* WB   = (u16*)ws;            off = 1u << 20;
    u16* BUFA = (u16*)(ws + off);    off += (size_t)NF * 256;   // Fh_m -> AGG_F (in place)
    u16* BUFB = (u16*)(ws + off);    off += (size_t)NV * 256;   // Vh_m, then Vh2 -> AGG_V
    u16* BUFC = (u16*)(ws + off);    off += (size_t)NF * 256;   // Fh2 (old-F table)
    float* Tbuf = (float*)BUFA;      // NF*512 B <= BUFA+BUFB+BUFC region
    int* rsF  = (int*)(ws + off);    off += (size_t)(NF + 1) * 4;
    int* rsV  = (int*)(ws + off);    off += (size_t)(NV + 1) * 4;
    int* curF = (int*)(ws + off);    off += (size_t)NF * 4;     // contiguous with curV
    int* curV = (int*)(ws + off);    off += (size_t)NV * 4;
    int* elF  = (int*)(ws + off);    off += (size_t)E * 4;
    int* elV  = (int*)(ws + off);    off += (size_t)E * 4;
    int* bsum = (int*)(ws + off);    off += 4096;
    float* mx    = (float*)(ws + off); off += (size_t)G * 4;
    float* dn    = (float*)(ws + off); off += (size_t)G * 4;
    float* g_att = (float*)(ws + off); off += (size_t)G * 512;
    float* gate  = (float*)(ws + off); off += (size_t)NF * 4;

    float* out_v = (float*)d_out;
    float* out_f = out_v + (size_t)NV * D;
    float* out_g = out_f + (size_t)NF * D;

    prep_w<<<(17 * 16384 + 255) / 256, 256, 0, stream>>>(Wm_vf, Wc_vf, Wm_fv, Wc_fv, Wtr, WB);
    hipMemcpyAsync(out_v, vars_in, (size_t)NV * D * 4, hipMemcpyDeviceToDevice, stream);
    hipMemcpyAsync(out_f, facs_in, (size_t)NF * D * 4, hipMemcpyDeviceToDevice, stream);

    // ---- CSR build (both directions), once per call ----
    const int GE = (E + 255) / 256;
    hipMemsetAsync(curF, 0, (size_t)(NF + NV) * 4, stream);
    hist_k<<<GE, 256, 0, stream>>>(e_src, e_dst, curV, curF, E);
    const int NBf = (NF + 1023) / 1024, NBv = (NV + 1023) / 1024;
    scan1_k<<<NBf, 256, 0, stream>>>(curF, rsF, bsum, NF);
    scan2_k<<<1, 256, 0, stream>>>(bsum, NBf);
    scan3_k<<<(NF + 256) / 256, 256, 0, stream>>>(rsF, bsum, NF, E);
    scan1_k<<<NBv, 256, 0, stream>>>(curV, rsV, bsum, NV);
    scan2_k<<<1, 256, 0, stream>>>(bsum, NBv);
    scan3_k<<<(NV + 256) / 256, 256, 0, stream>>>(rsV, bsum, NV, E);
    hipMemsetAsync(curF, 0, (size_t)(NF + NV) * 4, stream);
    fill_k<<<GE, 256, 0, stream>>>(e_src, e_dst, rsF, rsV, curF, curV, elF, elV, E);

    const int GBv = (NV + 63) / 64;
    const int GBf = (NF + 63) / 64;
    const int GAf = (NF + 3) / 4;
    const int GAv = (NV + 3) / 4;

    for (int l = 0; l < 2; l++) {
        u16* wb = WB + l * 8 * 16384;
        // F projections (old F): Fh_m = F@Wm_vf_top -> BUFA ; Fh2 = F@Wm_fv_bot -> BUFC
        gemm_dual<<<GBf, 256, 0, stream>>>(out_f, wb + 0 * 16384, wb + 3 * 16384, BUFA, BUFC, NF);
        // Vh_m = V@Wm_vf_bot -> BUFB
        gemm_k<false, false, false, false, true><<<GBv, 256, 0, stream>>>(
            out_v, nullptr, wb + 1 * 16384, nullptr, nullptr, nullptr, nullptr, BUFB, NV);
        // AGG_F = segsum relu(Fh_m[dst] + Vh_m[src] + bm_vf) (in place over BUFA)
        aggregate_k<<<GAf, 256, 0, stream>>>(BUFA, BUFB, rsF, elF, bm_vf + l * D, NF);
        // F = relu(F@Wc_top + AGG_F@Wc_bot + bc)
        gemm_k<true, true, true, false, false><<<GBf, 256, 0, stream>>>(
            out_f, BUFA, wb + 4 * 16384, wb + 5 * 16384, bc_vf + l * D, nullptr, out_f, nullptr, NF);
        // Vh2 = V@Wm_fv_top -> BUFB (V unchanged so far)
        gemm_k<false, false, false, false, true><<<GBv, 256, 0, stream>>>(
            out_v, nullptr, wb + 2 * 16384, nullptr, nullptr, nullptr, nullptr, BUFB, NV);
        // AGG_V = segsum relu(Vh2[src] + Fh2[dst] + bm_fv) (in place over BUFB)
        aggregate_k<<<GAv, 256, 0, stream>>>(BUFB, BUFC, rsV, elV, bm_fv + l * D, NV);
        // V = V + relu(V@Wc_top + AGG_V@Wc_bot + bc)
        gemm_k<true, true, true, true, false><<<GBv, 256, 0, stream>>>(
            out_v, BUFB, wb + 6 * 16384, wb + 7 * 16384, bc_fv + l * D, out_v, out_v, nullptr, NV);
    }

    // ---- global node ----
    gemm_k<false, false, false, false, false><<<GBf, 256, 0, stream>>>(
        out_f, nullptr, WB + 16 * 16384, nullptr, bt, nullptr, Tbuf, nullptr, NF);
    gate_k<<<(NF + 3) / 4, 256, 0, stream>>>(out_f, Wg, bg, gate, NF);
    gstats_k<<<G, 256, 0, stream>>>(gate, batch, mx, dn, NF);
    hipMemsetAsync(g_att, 0, (size_t)G * 512, stream);
    wsum_k<<<(NF + 255) / 256, 128, 0, stream>>>(gate, Tbuf, batch, mx, dn, g_att, NF);
    gfinal_k<<<G, 128, 0, stream>>>(g_att, Wl, bl, out_g);
}

// Round 4
// 1019.236 us; speedup vs baseline: 6.3575x; 1.1554x over previous
//
#include <hip/hip_runtime.h>
#include <hip/hip_bf16.h>

typedef unsigned short u16;
typedef unsigned int u32;
typedef __attribute__((ext_vector_type(4))) float f32x4;
typedef __attribute__((ext_vector_type(8))) __bf16 bf16x8;

__device__ __forceinline__ u16 f2bf(float f) {
    u32 x = __float_as_uint(f);
    u32 r = x + 0x7fffu + ((x >> 16) & 1u);   // round-to-nearest-even
    return (u16)(r >> 16);
}
__device__ __forceinline__ float bf2f(u16 u) {
    return __uint_as_float(((u32)u) << 16);
}

// -------------------------------------------------------------------------
// Weight prep: 17 matrices [128x128] transposed to bf16  Wt[c][k] = W[k][c]
// per layer l (base l*8): 0 Wm_vf_top, 1 Wm_vf_bot, 2 Wm_fv_top, 3 Wm_fv_bot,
// 4 Wc_vf_top, 5 Wc_vf_bot, 6 Wc_fv_top, 7 Wc_fv_bot; 16 = Wt.
// -------------------------------------------------------------------------
__global__ __launch_bounds__(256) void prep_w(
    const float* __restrict__ Wm_vf, const float* __restrict__ Wc_vf,
    const float* __restrict__ Wm_fv, const float* __restrict__ Wc_fv,
    const float* __restrict__ Wtr, u16* __restrict__ dst)
{
    int i = blockIdx.x * 256 + threadIdx.x;
    if (i >= 17 * 16384) return;
    int m = i >> 14;
    int r = i & 16383;
    int c = r >> 7;
    int k = r & 127;
    const float* p;
    if (m == 16) {
        p = Wtr;
    } else {
        int l = m >> 3, j = m & 7;
        const float* base = (j < 2) ? Wm_vf : (j < 4) ? Wm_fv : (j < 6) ? Wc_vf : Wc_fv;
        p = base + l * 32768 + (j & 1) * 16384;
    }
    dst[m * 16384 + c * 128 + k] = f2bf(p[k * 128 + c]);
}

// -------------------------------------------------------------------------
// CSR build, XCD-partitioned: blockIdx&7 selects a row-range partition
// (under round-robin dispatch this pins each row range's cache lines to one
// XCD's L2, killing partial-line write-back amplification). Each partition
// re-scans the edge list (L3-resident, cheap).
// -------------------------------------------------------------------------
#define EPB 2048

__global__ __launch_bounds__(256) void hist_part(
    const int* __restrict__ es, const int* __restrict__ ed,
    int* __restrict__ cntV, int* __restrict__ cntF,
    int E, int vChunk, int fChunk)
{
    int part = blockIdx.x & 7;
    int base = (blockIdx.x >> 3) * EPB;
    int end = base + EPB < E ? base + EPB : E;
    int vLo = part * vChunk, vHi = vLo + vChunk;
    int fLo = part * fChunk, fHi = fLo + fChunk;
    for (int i = base + threadIdx.x; i < end; i += 256) {
        int v = es[i], f = ed[i];
        if (v >= vLo && v < vHi) atomicAdd(&cntV[v], 1);
        if (f >= fLo && f < fHi) atomicAdd(&cntF[f], 1);
    }
}

// block scans 1024 elems (256 thr x 4), writes exclusive partials + block sum
__global__ __launch_bounds__(256) void scan1_k(
    const int* __restrict__ cnt, int* __restrict__ rs, int* __restrict__ bsum, int N)
{
    __shared__ int sd[256];
    int t = threadIdx.x;
    int b0 = blockIdx.x * 1024;
    int v[4]; int s = 0;
#pragma unroll
    for (int j = 0; j < 4; j++) { int i = b0 + t * 4 + j; v[j] = (i < N) ? cnt[i] : 0; s += v[j]; }
    sd[t] = s; __syncthreads();
    for (int off = 1; off < 256; off <<= 1) {
        int x = (t >= off) ? sd[t - off] : 0;
        __syncthreads();
        sd[t] += x;
        __syncthreads();
    }
    int excl = sd[t] - s;
    if (t == 255) bsum[blockIdx.x] = sd[255];
    int run = excl;
#pragma unroll
    for (int j = 0; j < 4; j++) { int i = b0 + t * 4 + j; if (i < N) rs[i] = run; run += v[j]; }
}

__global__ __launch_bounds__(256) void scan2_k(int* __restrict__ bsum, int NB)
{
    __shared__ int sd[256];
    int t = threadIdx.x;
    int s = (t < NB) ? bsum[t] : 0;
    sd[t] = s; __syncthreads();
    for (int off = 1; off < 256; off <<= 1) {
        int x = (t >= off) ? sd[t - off] : 0;
        __syncthreads();
        sd[t] += x;
        __syncthreads();
    }
    if (t < NB) bsum[t] = sd[t] - s;   // exclusive
}

__global__ __launch_bounds__(256) void scan3_k(
    int* __restrict__ rs, const int* __restrict__ bsum, int N, int E)
{
    int i = blockIdx.x * 256 + threadIdx.x;
    if (i < N) rs[i] += bsum[i >> 10];
    else if (i == N) rs[N] = E;
}

// fill consumes cnt via atomicSub (no cur arrays / second memset needed)
__global__ __launch_bounds__(256) void fill_part(
    const int* __restrict__ es, const int* __restrict__ ed,
    const int* __restrict__ rsF, const int* __restrict__ rsV,
    int* __restrict__ cntF, int* __restrict__ cntV,
    int* __restrict__ elF, int* __restrict__ elV,
    int E, int vChunk, int fChunk)
{
    int part = blockIdx.x & 7;
    int base = (blockIdx.x >> 3) * EPB;
    int end = base + EPB < E ? base + EPB : E;
    int vLo = part * vChunk, vHi = vLo + vChunk;
    int fLo = part * fChunk, fHi = fLo + fChunk;
    for (int i = base + threadIdx.x; i < end; i += 256) {
        int v = es[i], f = ed[i];
        if (f >= fLo && f < fHi) { int p = rsF[f] + atomicSub(&cntF[f], 1) - 1; elF[p] = v; }
        if (v >= vLo && v < vHi) { int p = rsV[v] + atomicSub(&cntV[v], 1) - 1; elV[p] = f; }
    }
}

// -------------------------------------------------------------------------
// CSR aggregation (one wave per row, 4x unrolled gathers):
//   OWN[w] <- bf16( sum_{o in adj(w)} relu(OWN[w] + OTH[o] + bias) )
// -------------------------------------------------------------------------
__global__ __launch_bounds__(256) void aggregate_k(
    u16* __restrict__ OWN, const u16* __restrict__ OTH,
    const int* __restrict__ rs, const int* __restrict__ el,
    const float* __restrict__ bias, int N)
{
    int row = blockIdx.x * 4 + (threadIdx.x >> 6);
    if (row >= N) return;
    int lane = threadIdx.x & 63;
    int start = rs[row], end = rs[row + 1];
    ushort2 h = *(const ushort2*)&OWN[(size_t)row * 128 + lane * 2];
    float2 bv = *(const float2*)&bias[lane * 2];
    float c0 = bf2f(h.x) + bv.x;
    float c1 = bf2f(h.y) + bv.y;
    float a0 = 0.f, a1 = 0.f;
    for (int p0 = start; p0 < end; p0 += 64) {
        int n = end - p0; if (n > 64) n = 64;
        int myidx = (lane < n) ? el[p0 + lane] : 0;
        int j = 0;
        for (; j + 4 <= n; j += 4) {
            int o0 = __shfl(myidx, j);
            int o1 = __shfl(myidx, j + 1);
            int o2 = __shfl(myidx, j + 2);
            int o3 = __shfl(myidx, j + 3);
            ushort2 b0 = *(const ushort2*)&OTH[(size_t)o0 * 128 + lane * 2];
            ushort2 b1 = *(const ushort2*)&OTH[(size_t)o1 * 128 + lane * 2];
            ushort2 b2 = *(const ushort2*)&OTH[(size_t)o2 * 128 + lane * 2];
            ushort2 b3 = *(const ushort2*)&OTH[(size_t)o3 * 128 + lane * 2];
            a0 += fmaxf(c0 + bf2f(b0.x), 0.f) + fmaxf(c0 + bf2f(b1.x), 0.f)
                + fmaxf(c0 + bf2f(b2.x), 0.f) + fmaxf(c0 + bf2f(b3.x), 0.f);
            a1 += fmaxf(c1 + bf2f(b0.y), 0.f) + fmaxf(c1 + bf2f(b1.y), 0.f)
                + fmaxf(c1 + bf2f(b2.y), 0.f) + fmaxf(c1 + bf2f(b3.y), 0.f);
        }
        for (; j < n; j++) {
            int o = __shfl(myidx, j);
            ushort2 b = *(const ushort2*)&OTH[(size_t)o * 128 + lane * 2];
            a0 += fmaxf(c0 + bf2f(b.x), 0.f);
            a1 += fmaxf(c1 + bf2f(b.y), 0.f);
        }
    }
    ushort2 r; r.x = f2bf(a0); r.y = f2bf(a1);
    *(ushort2*)&OWN[(size_t)row * 128 + lane * 2] = r;
}

// -------------------------------------------------------------------------
// GEMM: Y[N,128] = (RES? res +) maybe_relu( X1@W1 (+ X2@W2) + bias )
// X2 optionally bf16 (aggregate buffer). W transposed bf16 [c][k].
// -------------------------------------------------------------------------
template <bool TWO, bool X2BF, bool RELU, bool RES, bool OBF16>
__global__ __launch_bounds__(256) void gemm_k(
    const float* __restrict__ X1, const void* __restrict__ X2,
    const u16* __restrict__ W1, const u16* __restrict__ W2,
    const float* __restrict__ bias, const float* __restrict__ res,
    float* __restrict__ Yf, u16* __restrict__ Yb, int N)
{
    __shared__ __align__(16) u16 Xs[64 * 136];
    __shared__ __align__(16) u16 Ws[128 * 136];
    const int tid = threadIdx.x;
    const int lane = tid & 63;
    const int wv = tid >> 6;
    const int r0 = blockIdx.x * 64;

    f32x4 acc[8];
#pragma unroll
    for (int i = 0; i < 8; i++) acc[i] = (f32x4)0.f;

#pragma unroll
    for (int p = 0; p < (TWO ? 2 : 1); ++p) {
        const u16* __restrict__ W = (TWO && p) ? W2 : W1;
        if (p) __syncthreads();
        if (TWO && p && X2BF) {
            const u16* Xb = (const u16*)X2;
#pragma unroll
            for (int j = 0; j < 4; j++) {
                int q = j * 256 + tid;
                int row = q >> 4;
                int col = (q & 15) * 8;
                uint4 v = make_uint4(0, 0, 0, 0);
                int gr = r0 + row;
                if (gr < N) v = *(const uint4*)&Xb[(size_t)gr * 128 + col];
                *(uint4*)&Xs[row * 136 + col] = v;
            }
        } else {
            const float* __restrict__ X = (TWO && p) ? (const float*)X2 : X1;
#pragma unroll
            for (int j = 0; j < 8; j++) {
                int q = j * 256 + tid;
                int row = q >> 5;
                int col = (q & 31) * 4;
                float4 v = make_float4(0.f, 0.f, 0.f, 0.f);
                int gr = r0 + row;
                if (gr < N) v = *(const float4*)&X[(size_t)gr * 128 + col];
                ushort4 h;
                h.x = f2bf(v.x); h.y = f2bf(v.y); h.z = f2bf(v.z); h.w = f2bf(v.w);
                *(ushort4*)&Xs[row * 136 + col] = h;
            }
        }
#pragma unroll
        for (int j = 0; j < 8; j++) {
            int q = j * 256 + tid;
            int c = q >> 4;
            int k = (q & 15) * 8;
            uint4 w = *(const uint4*)&W[c * 128 + k];
            *(uint4*)&Ws[c * 136 + k] = w;
        }
        __syncthreads();
#pragma unroll
        for (int ks = 0; ks < 4; ks++) {
            bf16x8 a = *(const bf16x8*)&Xs[(wv * 16 + (lane & 15)) * 136 + ks * 32 + (lane >> 4) * 8];
#pragma unroll
            for (int ct = 0; ct < 8; ct++) {
                bf16x8 b = *(const bf16x8*)&Ws[(ct * 16 + (lane & 15)) * 136 + ks * 32 + (lane >> 4) * 8];
                acc[ct] = __builtin_amdgcn_mfma_f32_16x16x32_bf16(a, b, acc[ct], 0, 0, 0);
            }
        }
    }
#pragma unroll
    for (int ct = 0; ct < 8; ct++) {
        int col = ct * 16 + (lane & 15);
        float bv = bias ? bias[col] : 0.f;
#pragma unroll
        for (int r = 0; r < 4; r++) {
            int row = wv * 16 + (lane >> 4) * 4 + r;
            int gr = r0 + row;
            if (gr < N) {
                float v = acc[ct][r] + bv;
                if (RELU) v = fmaxf(v, 0.f);
                if (RES) v += res[(size_t)gr * 128 + col];
                if (OBF16) Yb[(size_t)gr * 128 + col] = f2bf(v);
                else       Yf[(size_t)gr * 128 + col] = v;
            }
        }
    }
}

// -------------------------------------------------------------------------
// Dual GEMM: stage X once, Y1 = X@W1, Y2 = X@W2 (both bf16 out, no bias).
// -------------------------------------------------------------------------
__global__ __launch_bounds__(256) void gemm_dual(
    const float* __restrict__ X, const u16* __restrict__ W1, const u16* __restrict__ W2,
    u16* __restrict__ Y1, u16* __restrict__ Y2, int N)
{
    __shared__ __align__(16) u16 Xs[64 * 136];
    __shared__ __align__(16) u16 Ws[128 * 136];
    const int tid = threadIdx.x;
    const int lane = tid & 63;
    const int wv = tid >> 6;
    const int r0 = blockIdx.x * 64;

    f32x4 acc1[8], acc2[8];
#pragma unroll
    for (int i = 0; i < 8; i++) { acc1[i] = (f32x4)0.f; acc2[i] = (f32x4)0.f; }

#pragma unroll
    for (int j = 0; j < 8; j++) {
        int q = j * 256 + tid;
        int row = q >> 5;
        int col = (q & 31) * 4;
        float4 v = make_float4(0.f, 0.f, 0.f, 0.f);
        int gr = r0 + row;
        if (gr < N) v = *(const float4*)&X[(size_t)gr * 128 + col];
        ushort4 h;
        h.x = f2bf(v.x); h.y = f2bf(v.y); h.z = f2bf(v.z); h.w = f2bf(v.w);
        *(ushort4*)&Xs[row * 136 + col] = h;
    }
#pragma unroll
    for (int p = 0; p < 2; ++p) {
        const u16* __restrict__ W = p ? W2 : W1;
        if (p) __syncthreads();
#pragma unroll
        for (int j = 0; j < 8; j++) {
            int q = j * 256 + tid;
            int c = q >> 4;
            int k = (q & 15) * 8;
            uint4 w = *(const uint4*)&W[c * 128 + k];
            *(uint4*)&Ws[c * 136 + k] = w;
        }
        __syncthreads();
#pragma unroll
        for (int ks = 0; ks < 4; ks++) {
            bf16x8 a = *(const bf16x8*)&Xs[(wv * 16 + (lane & 15)) * 136 + ks * 32 + (lane >> 4) * 8];
#pragma unroll
            for (int ct = 0; ct < 8; ct++) {
                bf16x8 b = *(const bf16x8*)&Ws[(ct * 16 + (lane & 15)) * 136 + ks * 32 + (lane >> 4) * 8];
                if (p) acc2[ct] = __builtin_amdgcn_mfma_f32_16x16x32_bf16(a, b, acc2[ct], 0, 0, 0);
                else   acc1[ct] = __builtin_amdgcn_mfma_f32_16x16x32_bf16(a, b, acc1[ct], 0, 0, 0);
            }
        }
    }
#pragma unroll
    for (int ct = 0; ct < 8; ct++) {
        int col = ct * 16 + (lane & 15);
#pragma unroll
        for (int r = 0; r < 4; r++) {
            int row = wv * 16 + (lane >> 4) * 4 + r;
            int gr = r0 + row;
            if (gr < N) {
                Y1[(size_t)gr * 128 + col] = f2bf(acc1[ct][r]);
                Y2[(size_t)gr * 128 + col] = f2bf(acc2[ct][r]);
            }
        }
    }
}

// -------------------------------------------------------------------------
// gate[f] = factors[f] . Wg + bg
// -------------------------------------------------------------------------
__global__ __launch_bounds__(256) void gate_k(
    const float* __restrict__ F, const float* __restrict__ Wg,
    const float* __restrict__ bg, float* __restrict__ gate, int NF)
{
    int lane = threadIdx.x & 63;
    int f = blockIdx.x * 4 + (threadIdx.x >> 6);
    if (f >= NF) return;
    float p = F[(size_t)f * 128 + lane] * Wg[lane]
            + F[(size_t)f * 128 + 64 + lane] * Wg[64 + lane];
#pragma unroll
    for (int off = 32; off; off >>= 1) p += __shfl_down(p, off);
    if (lane == 0) gate[f] = p + bg[0];
}

// -------------------------------------------------------------------------
// Per-group max + exp-sum of gate (batch sorted). One block per group.
// -------------------------------------------------------------------------
__global__ __launch_bounds__(256) void gstats_k(
    const float* __restrict__ gate, const int* __restrict__ batch,
    float* __restrict__ mx, float* __restrict__ dn, int NF)
{
    int g = blockIdx.x, tid = threadIdx.x;
    int lo = 0, hi = NF;
    while (lo < hi) { int mid = (lo + hi) >> 1; if (batch[mid] < g) lo = mid + 1; else hi = mid; }
    int start = lo;
    lo = start; hi = NF;
    while (lo < hi) { int mid = (lo + hi) >> 1; if (batch[mid] < g + 1) lo = mid + 1; else hi = mid; }
    int end = lo;

    __shared__ float red[256];
    float m = -3.4e38f;
    for (int i = start + tid; i < end; i += 256) m = fmaxf(m, gate[i]);
    red[tid] = m; __syncthreads();
    for (int s = 128; s; s >>= 1) { if (tid < s) red[tid] = fmaxf(red[tid], red[tid + s]); __syncthreads(); }
    float mval = red[0]; __syncthreads();
    float s = 0.f;
    for (int i = start + tid; i < end; i += 256) s += __expf(gate[i] - mval);
    red[tid] = s; __syncthreads();
    for (int t = 128; t; t >>= 1) { if (tid < t) red[tid] += red[tid + t]; __syncthreads(); }
    if (tid == 0) { mx[g] = mval; dn[g] = red[0]; }
}

// -------------------------------------------------------------------------
// Segmented weighted sum over sorted batch; atomic flush at segment edges.
// -------------------------------------------------------------------------
__global__ __launch_bounds__(128) void wsum_k(
    const float* __restrict__ gate, const float* __restrict__ T,
    const int* __restrict__ batch, const float* __restrict__ mx,
    const float* __restrict__ dn, float* __restrict__ g_att, int NF)
{
    int tid = threadIdx.x;
    int i0 = blockIdx.x * 256;
    if (i0 >= NF) return;
    int iend = i0 + 256; if (iend > NF) iend = NF;
    int curg = batch[i0];
    float acc = 0.f;
    for (int i = i0; i < iend; i++) {
        int g = batch[i];
        if (g != curg) {
            atomicAdd(&g_att[(size_t)curg * 128 + tid], acc);
            acc = 0.f; curg = g;
        }
        float w = __expf(gate[i] - mx[g]) / dn[g];
        acc += w * T[(size_t)i * 128 + tid];
    }
    atomicAdd(&g_att[(size_t)curg * 128 + tid], acc);
}

__global__ __launch_bounds__(128) void gfinal_k(
    const float* __restrict__ g_att, const float* __restrict__ Wl,
    const float* __restrict__ bl, float* __restrict__ out_g)
{
    int g = blockIdx.x, tid = threadIdx.x;
    __shared__ float ga[128];
    ga[tid] = g_att[(size_t)g * 128 + tid];
    __syncthreads();
    float o = bl[tid];
    for (int k = 0; k < 128; k++) o += ga[k] * Wl[k * 128 + tid];
    out_g[(size_t)g * 128 + tid] = fmaxf(o, 0.f);
}

// -------------------------------------------------------------------------
extern "C" void kernel_launch(void* const* d_in, const int* in_sizes, int n_in,
                              void* d_out, int out_size, void* d_ws, size_t ws_size,
                              hipStream_t stream)
{
    const int D = 128;
    const int NV = in_sizes[0] / D;
    const int NF = in_sizes[1] / D;
    const int E  = in_sizes[2] / 2;
    const int G  = out_size / D - NV - NF;

    const float* vars_in = (const float*)d_in[0];
    const float* facs_in = (const float*)d_in[1];
    const int*   eidx    = (const int*)d_in[2];
    const int*   e_src   = eidx;        // variable index per edge
    const int*   e_dst   = eidx + E;    // factor index per edge
    const int*   batch   = (const int*)d_in[4];
    const float* Wm_vf = (const float*)d_in[5],  *bm_vf = (const float*)d_in[6];
    const float* Wc_vf = (const float*)d_in[7],  *bc_vf = (const float*)d_in[8];
    const float* Wm_fv = (const float*)d_in[9],  *bm_fv = (const float*)d_in[10];
    const float* Wc_fv = (const float*)d_in[11], *bc_fv = (const float*)d_in[12];
    const float* Wg  = (const float*)d_in[13], *bg = (const float*)d_in[14];
    const float* Wtr = (const float*)d_in[15], *bt = (const float*)d_in[16];
    const float* Wl  = (const float*)d_in[17], *bl = (const float*)d_in[18];

    // workspace (~87 MB peak; 103.4 MB known-safe from round 2)
    char* ws = (char*)d_ws;
    size_t off = 0;
    u16* WB   = (u16*)ws;            off = 1u << 20;
    u16* BUFA = (u16*)(ws + off);    off += (size_t)NF * 256;   // Fh_m -> AGG_F (in place)
    u16* BUFB = (u16*)(ws + off);    off += (size_t)NV * 256;   // Vh_m, then Vh2 -> AGG_V
    u16* BUFC = (u16*)(ws + off);    off += (size_t)NF * 256;   // Fh2 (old-F table)
    float* Tbuf = (float*)BUFA;      // NF*512 B spans BUFA+BUFB (dead by then)
    int* rsF  = (int*)(ws + off);    off += (size_t)(NF + 1) * 4;
    int* rsV  = (int*)(ws + off);    off += (size_t)(NV + 1) * 4;
    int* cntF = (int*)(ws + off);    off += (size_t)NF * 4;     // contiguous with cntV
    int* cntV = (int*)(ws + off);    off += (size_t)NV * 4;
    int* elF  = (int*)(ws + off);    off += (size_t)E * 4;
    int* elV  = (int*)(ws + off);    off += (size_t)E * 4;
    int* bsum = (int*)(ws + off);    off += 4096;
    float* mx    = (float*)(ws + off); off += (size_t)G * 4;
    float* dn    = (float*)(ws + off); off += (size_t)G * 4;
    float* g_att = (float*)(ws + off); off += (size_t)G * 512;
    float* gate  = (float*)(ws + off); off += (size_t)NF * 4;

    float* out_v = (float*)d_out;
    float* out_f = out_v + (size_t)NV * D;
    float* out_g = out_f + (size_t)NF * D;

    prep_w<<<(17 * 16384 + 255) / 256, 256, 0, stream>>>(Wm_vf, Wc_vf, Wm_fv, Wc_fv, Wtr, WB);

    // ---- CSR build (both directions), XCD-partitioned ----
    const int vChunk = (NV + 7) / 8, fChunk = (NF + 7) / 8;
    const int CH = (E + EPB - 1) / EPB;
    hipMemsetAsync(cntF, 0, (size_t)(NF + NV) * 4, stream);
    hist_part<<<CH * 8, 256, 0, stream>>>(e_src, e_dst, cntV, cntF, E, vChunk, fChunk);
    const int NBf = (NF + 1023) / 1024, NBv = (NV + 1023) / 1024;
    scan1_k<<<NBf, 256, 0, stream>>>(cntF, rsF, bsum, NF);
    scan2_k<<<1, 256, 0, stream>>>(bsum, NBf);
    scan3_k<<<(NF + 256) / 256, 256, 0, stream>>>(rsF, bsum, NF, E);
    scan1_k<<<NBv, 256, 0, stream>>>(cntV, rsV, bsum, NV);
    scan2_k<<<1, 256, 0, stream>>>(bsum, NBv);
    scan3_k<<<(NV + 256) / 256, 256, 0, stream>>>(rsV, bsum, NV, E);
    fill_part<<<CH * 8, 256, 0, stream>>>(e_src, e_dst, rsF, rsV, cntF, cntV, elF, elV, E, vChunk, fChunk);

    const int GBv = (NV + 63) / 64;
    const int GBf = (NF + 63) / 64;
    const int GAf = (NF + 3) / 4;
    const int GAv = (NV + 3) / 4;

    for (int l = 0; l < 2; l++) {
        u16* wb = WB + l * 8 * 16384;
        const float* Fin = l ? out_f : facs_in;   // layer 0 reads inputs directly
        const float* Vin = l ? out_v : vars_in;
        // F projections (old F): Fh_m = F@Wm_vf_top -> BUFA ; Fh2 = F@Wm_fv_bot -> BUFC
        gemm_dual<<<GBf, 256, 0, stream>>>(Fin, wb + 0 * 16384, wb + 3 * 16384, BUFA, BUFC, NF);
        // Vh_m = V@Wm_vf_bot -> BUFB
        gemm_k<false, false, false, false, true><<<GBv, 256, 0, stream>>>(
            Vin, nullptr, wb + 1 * 16384, nullptr, nullptr, nullptr, nullptr, BUFB, NV);
        // AGG_F = segsum relu(Fh_m[dst] + Vh_m[src] + bm_vf)  (in place over BUFA)
        aggregate_k<<<GAf, 256, 0, stream>>>(BUFA, BUFB, rsF, elF, bm_vf + l * D, NF);
        // F_new = relu(F@Wc_top + AGG_F@Wc_bot + bc) -> out_f
        gemm_k<true, true, true, false, false><<<GBf, 256, 0, stream>>>(
            Fin, BUFA, wb + 4 * 16384, wb + 5 * 16384, bc_vf + l * D, nullptr, out_f, nullptr, NF);
        // Vh2 = V@Wm_fv_top -> BUFB (V unchanged so far)
        gemm_k<false, false, false, false, true><<<GBv, 256, 0, stream>>>(
            Vin, nullptr, wb + 2 * 16384, nullptr, nullptr, nullptr, nullptr, BUFB, NV);
        // AGG_V = segsum relu(Vh2[src] + Fh2[dst] + bm_fv)  (in place over BUFB)
        aggregate_k<<<GAv, 256, 0, stream>>>(BUFB, BUFC, rsV, elV, bm_fv + l * D, NV);
        // V_new = V + relu(V@Wc_top + AGG_V@Wc_bot + bc) -> out_v
        gemm_k<true, true, true, true, false><<<GBv, 256, 0, stream>>>(
            Vin, BUFB, wb + 6 * 16384, wb + 7 * 16384, bc_fv + l * D, Vin, out_v, nullptr, NV);
    }

    // ---- global node ----
    gemm_k<false, false, false, false, false><<<GBf, 256, 0, stream>>>(
        out_f, nullptr, WB + 16 * 16384, nullptr, bt, nullptr, Tbuf, nullptr, NF);
    gate_k<<<(NF + 3) / 4, 256, 0, stream>>>(out_f, Wg, bg, gate, NF);
    gstats_k<<<G, 256, 0, stream>>>(gate, batch, mx, dn, NF);
    hipMemsetAsync(g_att, 0, (size_t)G * 512, stream);
    wsum_k<<<(NF + 255) / 256, 128, 0, stream>>>(gate, Tbuf, batch, mx, dn, g_att, NF);
    gfinal_k<<<G, 128, 0, stream>>>(g_att, Wl, bl, out_g);
}

// Round 5
// 840.161 us; speedup vs baseline: 7.7125x; 1.2131x over previous
//
#include <hip/hip_runtime.h>
#include <hip/hip_bf16.h>

typedef unsigned short u16;
typedef unsigned int u32;
typedef __attribute__((ext_vector_type(4))) float f32x4;
typedef __attribute__((ext_vector_type(8))) __bf16 bf16x8;

__device__ __forceinline__ u16 f2bf(float f) {
    u32 x = __float_as_uint(f);
    u32 r = x + 0x7fffu + ((x >> 16) & 1u);   // round-to-nearest-even
    return (u16)(r >> 16);
}
__device__ __forceinline__ float bf2f(u16 u) {
    return __uint_as_float(((u32)u) << 16);
}

// -------------------------------------------------------------------------
// Weight prep: 16 matrices [128x128] transposed to bf16  Wt[c][k] = W[k][c]
// per layer l (base l*8): 0 Wm_vf_top, 1 Wm_vf_bot, 2 Wm_fv_top, 3 Wm_fv_bot,
// 4 Wc_vf_top, 5 Wc_vf_bot, 6 Wc_fv_top, 7 Wc_fv_bot.
// -------------------------------------------------------------------------
__global__ __launch_bounds__(256) void prep_w(
    const float* __restrict__ Wm_vf, const float* __restrict__ Wc_vf,
    const float* __restrict__ Wm_fv, const float* __restrict__ Wc_fv,
    u16* __restrict__ dst)
{
    int i = blockIdx.x * 256 + threadIdx.x;
    if (i >= 16 * 16384) return;
    int m = i >> 14;
    int r = i & 16383;
    int c = r >> 7;
    int k = r & 127;
    int l = m >> 3, j = m & 7;
    const float* base = (j < 2) ? Wm_vf : (j < 4) ? Wm_fv : (j < 6) ? Wc_vf : Wc_fv;
    const float* p = base + l * 32768 + (j & 1) * 16384;
    dst[m * 16384 + c * 128 + k] = f2bf(p[k * 128 + c]);
}

// -------------------------------------------------------------------------
// CSR build, XCD-partitioned (blockIdx&7 = row-range partition).
// -------------------------------------------------------------------------
#define EPB 2048

__global__ __launch_bounds__(256) void hist_part(
    const int* __restrict__ es, const int* __restrict__ ed,
    int* __restrict__ cntV, int* __restrict__ cntF,
    int E, int vChunk, int fChunk)
{
    int part = blockIdx.x & 7;
    int base = (blockIdx.x >> 3) * EPB;
    int end = base + EPB < E ? base + EPB : E;
    int vLo = part * vChunk, vHi = vLo + vChunk;
    int fLo = part * fChunk, fHi = fLo + fChunk;
    for (int i = base + threadIdx.x; i < end; i += 256) {
        int v = es[i], f = ed[i];
        if (v >= vLo && v < vHi) atomicAdd(&cntV[v], 1);
        if (f >= fLo && f < fHi) atomicAdd(&cntF[f], 1);
    }
}

__global__ __launch_bounds__(256) void scan1_k(
    const int* __restrict__ cnt, int* __restrict__ rs, int* __restrict__ bsum, int N)
{
    __shared__ int sd[256];
    int t = threadIdx.x;
    int b0 = blockIdx.x * 1024;
    int v[4]; int s = 0;
#pragma unroll
    for (int j = 0; j < 4; j++) { int i = b0 + t * 4 + j; v[j] = (i < N) ? cnt[i] : 0; s += v[j]; }
    sd[t] = s; __syncthreads();
    for (int off = 1; off < 256; off <<= 1) {
        int x = (t >= off) ? sd[t - off] : 0;
        __syncthreads();
        sd[t] += x;
        __syncthreads();
    }
    int excl = sd[t] - s;
    if (t == 255) bsum[blockIdx.x] = sd[255];
    int run = excl;
#pragma unroll
    for (int j = 0; j < 4; j++) { int i = b0 + t * 4 + j; if (i < N) rs[i] = run; run += v[j]; }
}

__global__ __launch_bounds__(256) void scan2_k(int* __restrict__ bsum, int NB)
{
    __shared__ int sd[256];
    int t = threadIdx.x;
    int s = (t < NB) ? bsum[t] : 0;
    sd[t] = s; __syncthreads();
    for (int off = 1; off < 256; off <<= 1) {
        int x = (t >= off) ? sd[t - off] : 0;
        __syncthreads();
        sd[t] += x;
        __syncthreads();
    }
    if (t < NB) bsum[t] = sd[t] - s;
}

__global__ __launch_bounds__(256) void scan3_k(
    int* __restrict__ rs, const int* __restrict__ bsum, int N, int E)
{
    int i = blockIdx.x * 256 + threadIdx.x;
    if (i < N) rs[i] += bsum[i >> 10];
    else if (i == N) rs[N] = E;
}

__global__ __launch_bounds__(256) void fill_part(
    const int* __restrict__ es, const int* __restrict__ ed,
    const int* __restrict__ rsF, const int* __restrict__ rsV,
    int* __restrict__ cntF, int* __restrict__ cntV,
    int* __restrict__ elF, int* __restrict__ elV,
    int E, int vChunk, int fChunk)
{
    int part = blockIdx.x & 7;
    int base = (blockIdx.x >> 3) * EPB;
    int end = base + EPB < E ? base + EPB : E;
    int vLo = part * vChunk, vHi = vLo + vChunk;
    int fLo = part * fChunk, fHi = fLo + fChunk;
    for (int i = base + threadIdx.x; i < end; i += 256) {
        int v = es[i], f = ed[i];
        if (f >= fLo && f < fHi) { int p = rsF[f] + atomicSub(&cntF[f], 1) - 1; elF[p] = v; }
        if (v >= vLo && v < vHi) { int p = rsV[v] + atomicSub(&cntV[v], 1) - 1; elV[p] = f; }
    }
}

// -------------------------------------------------------------------------
// CSR aggregation (one wave per row, 8x/4x unrolled gathers):
//   OWN[w] <- bf16( sum_{o in adj(w)} relu(OWN[w] + OTH[o] + bias) )
// -------------------------------------------------------------------------
__global__ __launch_bounds__(256) void aggregate_k(
    u16* __restrict__ OWN, const u16* __restrict__ OTH,
    const int* __restrict__ rs, const int* __restrict__ el,
    const float* __restrict__ bias, int N)
{
    int row = blockIdx.x * 4 + (threadIdx.x >> 6);
    if (row >= N) return;
    int lane = threadIdx.x & 63;
    int start = rs[row], end = rs[row + 1];
    ushort2 h = *(const ushort2*)&OWN[(size_t)row * 128 + lane * 2];
    float2 bv = *(const float2*)&bias[lane * 2];
    float c0 = bf2f(h.x) + bv.x;
    float c1 = bf2f(h.y) + bv.y;
    float a0 = 0.f, a1 = 0.f;
    for (int p0 = start; p0 < end; p0 += 64) {
        int n = end - p0; if (n > 64) n = 64;
        int myidx = (lane < n) ? el[p0 + lane] : 0;
        int j = 0;
        for (; j + 8 <= n; j += 8) {
            ushort2 b0 = *(const ushort2*)&OTH[(size_t)__shfl(myidx, j)     * 128 + lane * 2];
            ushort2 b1 = *(const ushort2*)&OTH[(size_t)__shfl(myidx, j + 1) * 128 + lane * 2];
            ushort2 b2 = *(const ushort2*)&OTH[(size_t)__shfl(myidx, j + 2) * 128 + lane * 2];
            ushort2 b3 = *(const ushort2*)&OTH[(size_t)__shfl(myidx, j + 3) * 128 + lane * 2];
            ushort2 b4 = *(const ushort2*)&OTH[(size_t)__shfl(myidx, j + 4) * 128 + lane * 2];
            ushort2 b5 = *(const ushort2*)&OTH[(size_t)__shfl(myidx, j + 5) * 128 + lane * 2];
            ushort2 b6 = *(const ushort2*)&OTH[(size_t)__shfl(myidx, j + 6) * 128 + lane * 2];
            ushort2 b7 = *(const ushort2*)&OTH[(size_t)__shfl(myidx, j + 7) * 128 + lane * 2];
            a0 += fmaxf(c0 + bf2f(b0.x), 0.f) + fmaxf(c0 + bf2f(b1.x), 0.f)
                + fmaxf(c0 + bf2f(b2.x), 0.f) + fmaxf(c0 + bf2f(b3.x), 0.f)
                + fmaxf(c0 + bf2f(b4.x), 0.f) + fmaxf(c0 + bf2f(b5.x), 0.f)
                + fmaxf(c0 + bf2f(b6.x), 0.f) + fmaxf(c0 + bf2f(b7.x), 0.f);
            a1 += fmaxf(c1 + bf2f(b0.y), 0.f) + fmaxf(c1 + bf2f(b1.y), 0.f)
                + fmaxf(c1 + bf2f(b2.y), 0.f) + fmaxf(c1 + bf2f(b3.y), 0.f)
                + fmaxf(c1 + bf2f(b4.y), 0.f) + fmaxf(c1 + bf2f(b5.y), 0.f)
                + fmaxf(c1 + bf2f(b6.y), 0.f) + fmaxf(c1 + bf2f(b7.y), 0.f);
        }
        for (; j + 4 <= n; j += 4) {
            ushort2 b0 = *(const ushort2*)&OTH[(size_t)__shfl(myidx, j)     * 128 + lane * 2];
            ushort2 b1 = *(const ushort2*)&OTH[(size_t)__shfl(myidx, j + 1) * 128 + lane * 2];
            ushort2 b2 = *(const ushort2*)&OTH[(size_t)__shfl(myidx, j + 2) * 128 + lane * 2];
            ushort2 b3 = *(const ushort2*)&OTH[(size_t)__shfl(myidx, j + 3) * 128 + lane * 2];
            a0 += fmaxf(c0 + bf2f(b0.x), 0.f) + fmaxf(c0 + bf2f(b1.x), 0.f)
                + fmaxf(c0 + bf2f(b2.x), 0.f) + fmaxf(c0 + bf2f(b3.x), 0.f);
            a1 += fmaxf(c1 + bf2f(b0.y), 0.f) + fmaxf(c1 + bf2f(b1.y), 0.f)
                + fmaxf(c1 + bf2f(b2.y), 0.f) + fmaxf(c1 + bf2f(b3.y), 0.f);
        }
        for (; j < n; j++) {
            ushort2 b = *(const ushort2*)&OTH[(size_t)__shfl(myidx, j) * 128 + lane * 2];
            a0 += fmaxf(c0 + bf2f(b.x), 0.f);
            a1 += fmaxf(c1 + bf2f(b.y), 0.f);
        }
    }
    ushort2 r; r.x = f2bf(a0); r.y = f2bf(a1);
    *(ushort2*)&OWN[(size_t)row * 128 + lane * 2] = r;
}

// -------------------------------------------------------------------------
// GEMM building blocks (shared-memory tiles passed in).
// -------------------------------------------------------------------------
__device__ __forceinline__ void stage_Xf(const float* __restrict__ X, int r0, int N,
                                         u16* __restrict__ Xs, int tid)
{
#pragma unroll
    for (int j = 0; j < 8; j++) {
        int q = j * 256 + tid;
        int row = q >> 5;
        int col = (q & 31) * 4;
        float4 v = make_float4(0.f, 0.f, 0.f, 0.f);
        int gr = r0 + row;
        if (gr < N) v = *(const float4*)&X[(size_t)gr * 128 + col];
        ushort4 h;
        h.x = f2bf(v.x); h.y = f2bf(v.y); h.z = f2bf(v.z); h.w = f2bf(v.w);
        *(ushort4*)&Xs[row * 136 + col] = h;
    }
}
__device__ __forceinline__ void stage_Xb(const u16* __restrict__ X, int r0, int N,
                                         u16* __restrict__ Xs, int tid)
{
#pragma unroll
    for (int j = 0; j < 4; j++) {
        int q = j * 256 + tid;
        int row = q >> 4;
        int col = (q & 15) * 8;
        uint4 v = make_uint4(0, 0, 0, 0);
        int gr = r0 + row;
        if (gr < N) v = *(const uint4*)&X[(size_t)gr * 128 + col];
        *(uint4*)&Xs[row * 136 + col] = v;
    }
}
__device__ __forceinline__ void stage_W(const u16* __restrict__ W, u16* __restrict__ Ws, int tid)
{
#pragma unroll
    for (int j = 0; j < 8; j++) {
        int q = j * 256 + tid;
        int c = q >> 4;
        int k = (q & 15) * 8;
        *(uint4*)&Ws[c * 136 + k] = *(const uint4*)&W[c * 128 + k];
    }
}
__device__ __forceinline__ void mfma8(const u16* __restrict__ Xs, const u16* __restrict__ Ws,
                                      int lane, int wv, f32x4* acc)
{
#pragma unroll
    for (int ks = 0; ks < 4; ks++) {
        bf16x8 a = *(const bf16x8*)&Xs[(wv * 16 + (lane & 15)) * 136 + ks * 32 + (lane >> 4) * 8];
#pragma unroll
        for (int ct = 0; ct < 8; ct++) {
            bf16x8 b = *(const bf16x8*)&Ws[(ct * 16 + (lane & 15)) * 136 + ks * 32 + (lane >> 4) * 8];
            acc[ct] = __builtin_amdgcn_mfma_f32_16x16x32_bf16(a, b, acc[ct], 0, 0, 0);
        }
    }
}

// -------------------------------------------------------------------------
// proj3: blocks [0,GBf): Fh_m = F@W0 -> BUFA, Fh2 = F@W3 -> BUFC (dual);
//        blocks [GBf,..): Vh_m = V@W1 -> BUFB.   All bf16 out.
// -------------------------------------------------------------------------
__global__ __launch_bounds__(256) void proj3_k(
    const float* __restrict__ F, const float* __restrict__ V,
    const u16* __restrict__ W0, const u16* __restrict__ W3, const u16* __restrict__ W1,
    u16* __restrict__ BUFA, u16* __restrict__ BUFC, u16* __restrict__ BUFB,
    int NF, int NV, int GBf)
{
    __shared__ __align__(16) u16 Xs[64 * 136];
    __shared__ __align__(16) u16 Ws[128 * 136];
    const int tid = threadIdx.x, lane = tid & 63, wv = tid >> 6;
    if ((int)blockIdx.x < GBf) {
        const int r0 = blockIdx.x * 64;
        f32x4 acc1[8], acc2[8];
#pragma unroll
        for (int i = 0; i < 8; i++) { acc1[i] = (f32x4)0.f; acc2[i] = (f32x4)0.f; }
        stage_Xf(F, r0, NF, Xs, tid);
        stage_W(W0, Ws, tid);
        __syncthreads();
        mfma8(Xs, Ws, lane, wv, acc1);
        __syncthreads();
        stage_W(W3, Ws, tid);
        __syncthreads();
        mfma8(Xs, Ws, lane, wv, acc2);
#pragma unroll
        for (int ct = 0; ct < 8; ct++) {
            int col = ct * 16 + (lane & 15);
#pragma unroll
            for (int r = 0; r < 4; r++) {
                int gr = r0 + wv * 16 + (lane >> 4) * 4 + r;
                if (gr < NF) {
                    BUFA[(size_t)gr * 128 + col] = f2bf(acc1[ct][r]);
                    BUFC[(size_t)gr * 128 + col] = f2bf(acc2[ct][r]);
                }
            }
        }
    } else {
        const int r0 = (blockIdx.x - GBf) * 64;
        f32x4 acc[8];
#pragma unroll
        for (int i = 0; i < 8; i++) acc[i] = (f32x4)0.f;
        stage_Xf(V, r0, NV, Xs, tid);
        stage_W(W1, Ws, tid);
        __syncthreads();
        mfma8(Xs, Ws, lane, wv, acc);
#pragma unroll
        for (int ct = 0; ct < 8; ct++) {
            int col = ct * 16 + (lane & 15);
#pragma unroll
            for (int r = 0; r < 4; r++) {
                int gr = r0 + wv * 16 + (lane >> 4) * 4 + r;
                if (gr < NV) BUFB[(size_t)gr * 128 + col] = f2bf(acc[ct][r]);
            }
        }
    }
}

// -------------------------------------------------------------------------
// mixF: blocks [0,GBf): F_new = relu(F@W4 + AGG@W5 + bc) -> out_f (f32);
//       optionally gate[row] = F_new . Wg + bg (fused, layer L-1 only).
//       blocks [GBf,..): Vh2 = V@W2 -> BUFB (bf16).
// -------------------------------------------------------------------------
template <bool GATE>
__global__ __launch_bounds__(256) void mixF_k(
    const float* __restrict__ Fin, const u16* __restrict__ AGG,
    const u16* __restrict__ W4, const u16* __restrict__ W5,
    const float* __restrict__ bc, float* __restrict__ out_f,
    const float* __restrict__ Vin, const u16* __restrict__ W2,
    u16* __restrict__ BUFB,
    const float* __restrict__ Wg, const float* __restrict__ bg,
    float* __restrict__ gate, int NF, int NV, int GBf)
{
    __shared__ __align__(16) u16 Xs[64 * 136];
    __shared__ __align__(16) u16 Ws[128 * 136];
    const int tid = threadIdx.x, lane = tid & 63, wv = tid >> 6;
    if ((int)blockIdx.x < GBf) {
        const int r0 = blockIdx.x * 64;
        f32x4 acc[8];
#pragma unroll
        for (int i = 0; i < 8; i++) acc[i] = (f32x4)0.f;
        stage_Xf(Fin, r0, NF, Xs, tid);
        stage_W(W4, Ws, tid);
        __syncthreads();
        mfma8(Xs, Ws, lane, wv, acc);
        __syncthreads();
        stage_Xb(AGG, r0, NF, Xs, tid);
        stage_W(W5, Ws, tid);
        __syncthreads();
        mfma8(Xs, Ws, lane, wv, acc);
        float gp[4] = {0.f, 0.f, 0.f, 0.f};
#pragma unroll
        for (int ct = 0; ct < 8; ct++) {
            int col = ct * 16 + (lane & 15);
            float bv = bc[col];
            float wgv = GATE ? Wg[col] : 0.f;
#pragma unroll
            for (int r = 0; r < 4; r++) {
                int gr = r0 + wv * 16 + (lane >> 4) * 4 + r;
                if (gr < NF) {
                    float v = fmaxf(acc[ct][r] + bv, 0.f);
                    out_f[(size_t)gr * 128 + col] = v;
                    if (GATE) gp[r] += v * wgv;
                }
            }
        }
        if (GATE) {
#pragma unroll
            for (int r = 0; r < 4; r++) {
                gp[r] += __shfl_xor(gp[r], 1);
                gp[r] += __shfl_xor(gp[r], 2);
                gp[r] += __shfl_xor(gp[r], 4);
                gp[r] += __shfl_xor(gp[r], 8);
            }
            if ((lane & 15) == 0) {
                float b0 = bg[0];
#pragma unroll
                for (int r = 0; r < 4; r++) {
                    int gr = r0 + wv * 16 + (lane >> 4) * 4 + r;
                    if (gr < NF) gate[gr] = gp[r] + b0;
                }
            }
        }
    } else {
        const int r0 = (blockIdx.x - GBf) * 64;
        f32x4 acc[8];
#pragma unroll
        for (int i = 0; i < 8; i++) acc[i] = (f32x4)0.f;
        stage_Xf(Vin, r0, NV, Xs, tid);
        stage_W(W2, Ws, tid);
        __syncthreads();
        mfma8(Xs, Ws, lane, wv, acc);
#pragma unroll
        for (int ct = 0; ct < 8; ct++) {
            int col = ct * 16 + (lane & 15);
#pragma unroll
            for (int r = 0; r < 4; r++) {
                int gr = r0 + wv * 16 + (lane >> 4) * 4 + r;
                if (gr < NV) BUFB[(size_t)gr * 128 + col] = f2bf(acc[ct][r]);
            }
        }
    }
}

// -------------------------------------------------------------------------
// combineV: V_new = V + relu(V@W6 + AGG@W7 + bc) -> out_v (f32)
// -------------------------------------------------------------------------
__global__ __launch_bounds__(256) void combineV_k(
    const float* __restrict__ Vin, const u16* __restrict__ AGG,
    const u16* __restrict__ W6, const u16* __restrict__ W7,
    const float* __restrict__ bc, float* __restrict__ out_v, int NV)
{
    __shared__ __align__(16) u16 Xs[64 * 136];
    __shared__ __align__(16) u16 Ws[128 * 136];
    const int tid = threadIdx.x, lane = tid & 63, wv = tid >> 6;
    const int r0 = blockIdx.x * 64;
    f32x4 acc[8];
#pragma unroll
    for (int i = 0; i < 8; i++) acc[i] = (f32x4)0.f;
    stage_Xf(Vin, r0, NV, Xs, tid);
    stage_W(W6, Ws, tid);
    __syncthreads();
    mfma8(Xs, Ws, lane, wv, acc);
    __syncthreads();
    stage_Xb(AGG, r0, NV, Xs, tid);
    stage_W(W7, Ws, tid);
    __syncthreads();
    mfma8(Xs, Ws, lane, wv, acc);
#pragma unroll
    for (int ct = 0; ct < 8; ct++) {
        int col = ct * 16 + (lane & 15);
        float bv = bc[col];
#pragma unroll
        for (int r = 0; r < 4; r++) {
            int gr = r0 + wv * 16 + (lane >> 4) * 4 + r;
            if (gr < NV) {
                float v = fmaxf(acc[ct][r] + bv, 0.f) + Vin[(size_t)gr * 128 + col];
                out_v[(size_t)gr * 128 + col] = v;
            }
        }
    }
}

// -------------------------------------------------------------------------
// gstats: per-group softmax over gate, normalized in place (gate -> attn).
// dn[g]=denominator (0 for empty groups).
// -------------------------------------------------------------------------
__global__ __launch_bounds__(256) void gstats_k(
    float* __restrict__ gate, const int* __restrict__ batch,
    float* __restrict__ dn, int NF)
{
    int g = blockIdx.x, tid = threadIdx.x;
    int lo = 0, hi = NF;
    while (lo < hi) { int mid = (lo + hi) >> 1; if (batch[mid] < g) lo = mid + 1; else hi = mid; }
    int start = lo;
    lo = start; hi = NF;
    while (lo < hi) { int mid = (lo + hi) >> 1; if (batch[mid] < g + 1) lo = mid + 1; else hi = mid; }
    int end = lo;

    __shared__ float red[256];
    float m = -3.4e38f;
    for (int i = start + tid; i < end; i += 256) m = fmaxf(m, gate[i]);
    red[tid] = m; __syncthreads();
    for (int s = 128; s; s >>= 1) { if (tid < s) red[tid] = fmaxf(red[tid], red[tid + s]); __syncthreads(); }
    float mval = red[0]; __syncthreads();
    float s = 0.f;
    for (int i = start + tid; i < end; i += 256) {
        float e = __expf(gate[i] - mval);
        gate[i] = e;
        s += e;
    }
    red[tid] = s; __syncthreads();
    for (int t = 128; t; t >>= 1) { if (tid < t) red[tid] += red[tid + t]; __syncthreads(); }
    float denom = red[0];
    if (tid == 0) dn[g] = denom;
    float rdn = (denom > 0.f) ? 1.f / denom : 0.f;
    for (int i = start + tid; i < end; i += 256) gate[i] *= rdn;
}

// -------------------------------------------------------------------------
// wsum: g_att[g] += sum_i attn[i] * F[i]  over 32-row chunks (sorted batch).
// -------------------------------------------------------------------------
__global__ __launch_bounds__(128) void wsum_k(
    const float* __restrict__ attn, const float* __restrict__ F,
    const int* __restrict__ batch, float* __restrict__ g_att, int NF)
{
    int tid = threadIdx.x;
    int i0 = blockIdx.x * 32;
    if (i0 >= NF) return;
    int iend = i0 + 32; if (iend > NF) iend = NF;
    int curg = batch[i0];
    float acc = 0.f;
    for (int i = i0; i < iend; i++) {
        int g = batch[i];
        if (g != curg) {
            atomicAdd(&g_att[(size_t)curg * 128 + tid], acc);
            acc = 0.f; curg = g;
        }
        acc += attn[i] * F[(size_t)i * 128 + tid];
    }
    atomicAdd(&g_att[(size_t)curg * 128 + tid], acc);
}

// -------------------------------------------------------------------------
// gfinal: t = (nonempty? g_att@Wt + bt : 0); out = relu(t@Wl_top + bl)
// (valid because attn sums to 1 per non-empty group).
// -------------------------------------------------------------------------
__global__ __launch_bounds__(128) void gfinal_k(
    const float* __restrict__ g_att, const float* __restrict__ dn,
    const float* __restrict__ Wt, const float* __restrict__ bt,
    const float* __restrict__ Wl, const float* __restrict__ bl,
    float* __restrict__ out_g)
{
    int g = blockIdx.x, tid = threadIdx.x;
    __shared__ float ga[128], tt[128];
    ga[tid] = g_att[(size_t)g * 128 + tid];
    __syncthreads();
    float t = 0.f;
    for (int k = 0; k < 128; k++) t += ga[k] * Wt[k * 128 + tid];
    bool nonempty = dn[g] > 0.f;
    t = nonempty ? t + bt[tid] : 0.f;
    tt[tid] = t; __syncthreads();
    float o = bl[tid];
    for (int k = 0; k < 128; k++) o += tt[k] * Wl[k * 128 + tid];
    out_g[(size_t)g * 128 + tid] = fmaxf(o, 0.f);
}

// -------------------------------------------------------------------------
extern "C" void kernel_launch(void* const* d_in, const int* in_sizes, int n_in,
                              void* d_out, int out_size, void* d_ws, size_t ws_size,
                              hipStream_t stream)
{
    const int D = 128;
    const int NV = in_sizes[0] / D;
    const int NF = in_sizes[1] / D;
    const int E  = in_sizes[2] / 2;
    const int G  = out_size / D - NV - NF;

    const float* vars_in = (const float*)d_in[0];
    const float* facs_in = (const float*)d_in[1];
    const int*   eidx    = (const int*)d_in[2];
    const int*   e_src   = eidx;        // variable index per edge
    const int*   e_dst   = eidx + E;    // factor index per edge
    const int*   batch   = (const int*)d_in[4];
    const float* Wm_vf = (const float*)d_in[5],  *bm_vf = (const float*)d_in[6];
    const float* Wc_vf = (const float*)d_in[7],  *bc_vf = (const float*)d_in[8];
    const float* Wm_fv = (const float*)d_in[9],  *bm_fv = (const float*)d_in[10];
    const float* Wc_fv = (const float*)d_in[11], *bc_fv = (const float*)d_in[12];
    const float* Wg  = (const float*)d_in[13], *bg = (const float*)d_in[14];
    const float* Wtr = (const float*)d_in[15], *bt = (const float*)d_in[16];
    const float* Wl  = (const float*)d_in[17], *bl = (const float*)d_in[18];

    // workspace (~86 MB peak; 103.4 MB known-safe)
    char* ws = (char*)d_ws;
    size_t off = 0;
    u16* WB   = (u16*)ws;            off = 1u << 20;
    u16* BUFA = (u16*)(ws + off);    off += (size_t)NF * 256;
    u16* BUFB = (u16*)(ws + off);    off += (size_t)NV * 256;
    u16* BUFC = (u16*)(ws + off);    off += (size_t)NF * 256;
    int* rsF  = (int*)(ws + off);    off += (size_t)(NF + 1) * 4;
    int* rsV  = (int*)(ws + off);    off += (size_t)(NV + 1) * 4;
    int* cntF = (int*)(ws + off);    off += (size_t)NF * 4;     // contiguous with cntV
    int* cntV = (int*)(ws + off);    off += (size_t)NV * 4;
    int* elF  = (int*)(ws + off);    off += (size_t)E * 4;
    int* elV  = (int*)(ws + off);    off += (size_t)E * 4;
    int* bsum = (int*)(ws + off);    off += 4096;
    float* dn    = (float*)(ws + off); off += (size_t)G * 4;
    float* g_att = (float*)(ws + off); off += (size_t)G * 512;
    float* gate  = (float*)(ws + off); off += (size_t)NF * 4;

    float* out_v = (float*)d_out;
    float* out_f = out_v + (size_t)NV * D;
    float* out_g = out_f + (size_t)NF * D;

    prep_w<<<(16 * 16384 + 255) / 256, 256, 0, stream>>>(Wm_vf, Wc_vf, Wm_fv, Wc_fv, WB);

    // ---- CSR build (both directions), XCD-partitioned ----
    const int vChunk = (NV + 7) / 8, fChunk = (NF + 7) / 8;
    const int CH = (E + EPB - 1) / EPB;
    hipMemsetAsync(cntF, 0, (size_t)(NF + NV) * 4, stream);
    hist_part<<<CH * 8, 256, 0, stream>>>(e_src, e_dst, cntV, cntF, E, vChunk, fChunk);
    const int NBf = (NF + 1023) / 1024, NBv = (NV + 1023) / 1024;
    scan1_k<<<NBf, 256, 0, stream>>>(cntF, rsF, bsum, NF);
    scan2_k<<<1, 256, 0, stream>>>(bsum, NBf);
    scan3_k<<<(NF + 256) / 256, 256, 0, stream>>>(rsF, bsum, NF, E);
    scan1_k<<<NBv, 256, 0, stream>>>(cntV, rsV, bsum, NV);
    scan2_k<<<1, 256, 0, stream>>>(bsum, NBv);
    scan3_k<<<(NV + 256) / 256, 256, 0, stream>>>(rsV, bsum, NV, E);
    fill_part<<<CH * 8, 256, 0, stream>>>(e_src, e_dst, rsF, rsV, cntF, cntV, elF, elV, E, vChunk, fChunk);

    const int GBv = (NV + 63) / 64;
    const int GBf = (NF + 63) / 64;
    const int GAf = (NF + 3) / 4;
    const int GAv = (NV + 3) / 4;

    for (int l = 0; l < 2; l++) {
        u16* wb = WB + l * 8 * 16384;
        const float* Fin = l ? out_f : facs_in;
        const float* Vin = l ? out_v : vars_in;
        // projections: Fh_m -> BUFA, Fh2 -> BUFC, Vh_m -> BUFB
        proj3_k<<<GBf + GBv, 256, 0, stream>>>(
            Fin, Vin, wb + 0 * 16384, wb + 3 * 16384, wb + 1 * 16384,
            BUFA, BUFC, BUFB, NF, NV, GBf);
        // AGG_F = segsum relu(Fh_m[dst] + Vh_m[src] + bm_vf)  (in place, BUFA)
        aggregate_k<<<GAf, 256, 0, stream>>>(BUFA, BUFB, rsF, elF, bm_vf + l * D, NF);
        // F_new -> out_f (+ fused gate on last layer); Vh2 -> BUFB
        if (l == 0)
            mixF_k<false><<<GBf + GBv, 256, 0, stream>>>(
                Fin, BUFA, wb + 4 * 16384, wb + 5 * 16384, bc_vf + l * D, out_f,
                Vin, wb + 2 * 16384, BUFB, nullptr, nullptr, nullptr, NF, NV, GBf);
        else
            mixF_k<true><<<GBf + GBv, 256, 0, stream>>>(
                Fin, BUFA, wb + 4 * 16384, wb + 5 * 16384, bc_vf + l * D, out_f,
                Vin, wb + 2 * 16384, BUFB, Wg, bg, gate, NF, NV, GBf);
        // AGG_V = segsum relu(Vh2[src] + Fh2[dst] + bm_fv)  (in place, BUFB)
        aggregate_k<<<GAv, 256, 0, stream>>>(BUFB, BUFC, rsV, elV, bm_fv + l * D, NV);
        // V_new = V + relu(...) -> out_v
        combineV_k<<<GBv, 256, 0, stream>>>(
            Vin, BUFB, wb + 6 * 16384, wb + 7 * 16384, bc_fv + l * D, out_v, NV);
    }

    // ---- global node ----
    gstats_k<<<G, 256, 0, stream>>>(gate, batch, dn, NF);
    hipMemsetAsync(g_att, 0, (size_t)G * 512, stream);
    wsum_k<<<(NF + 31) / 32, 128, 0, stream>>>(gate, out_f, batch, g_att, NF);
    gfinal_k<<<G, 128, 0, stream>>>(g_att, dn, Wtr, bt, Wl, bl, out_g);
}

// Round 6
// 829.288 us; speedup vs baseline: 7.8137x; 1.0131x over previous
//
#include <hip/hip_runtime.h>
#include <hip/hip_bf16.h>

typedef unsigned short u16;
typedef unsigned int u32;
typedef __attribute__((ext_vector_type(4))) float f32x4;
typedef __attribute__((ext_vector_type(8))) __bf16 bf16x8;

__device__ __forceinline__ u16 f2bf(float f) {
    u32 x = __float_as_uint(f);
    u32 r = x + 0x7fffu + ((x >> 16) & 1u);   // round-to-nearest-even
    return (u16)(r >> 16);
}
__device__ __forceinline__ float bf2f(u16 u) {
    return __uint_as_float(((u32)u) << 16);
}

// -------------------------------------------------------------------------
// setup: weight prep (16 matrices transposed to bf16) + zero cnt arrays.
// per layer l (base l*8): 0 Wm_vf_top, 1 Wm_vf_bot, 2 Wm_fv_top, 3 Wm_fv_bot,
// 4 Wc_vf_top, 5 Wc_vf_bot, 6 Wc_fv_top, 7 Wc_fv_bot.
// -------------------------------------------------------------------------
__global__ __launch_bounds__(256) void setup_k(
    const float* __restrict__ Wm_vf, const float* __restrict__ Wc_vf,
    const float* __restrict__ Wm_fv, const float* __restrict__ Wc_fv,
    u16* __restrict__ dst, int* __restrict__ cnt, int cntN)
{
    int i = blockIdx.x * 256 + threadIdx.x;
    if (i < 16 * 16384) {
        int m = i >> 14;
        int r = i & 16383;
        int c = r >> 7;
        int k = r & 127;
        int l = m >> 3, j = m & 7;
        const float* base = (j < 2) ? Wm_vf : (j < 4) ? Wm_fv : (j < 6) ? Wc_vf : Wc_fv;
        const float* p = base + l * 32768 + (j & 1) * 16384;
        dst[m * 16384 + c * 128 + k] = f2bf(p[k * 128 + c]);
    } else {
        int z = i - 16 * 16384;
        if (z < cntN) cnt[z] = 0;
    }
}

// -------------------------------------------------------------------------
// CSR build, XCD-partitioned with PERSISTENT all-resident blocks:
// grid = 8 * NPB; blockIdx&7 = partition (pinned to one XCD under
// round-robin dispatch since all blocks are co-resident from t=0);
// blockIdx>>3 = slot, grid-strides over edge chunks.
// -------------------------------------------------------------------------
#define EPB 2048
#define NPB 128

__global__ __launch_bounds__(256) void hist_part(
    const int* __restrict__ es, const int* __restrict__ ed,
    int* __restrict__ cntV, int* __restrict__ cntF,
    int E, int CH, int vChunk, int fChunk)
{
    int part = blockIdx.x & 7;
    int vLo = part * vChunk, vHi = vLo + vChunk;
    int fLo = part * fChunk, fHi = fLo + fChunk;
    for (int c = blockIdx.x >> 3; c < CH; c += NPB) {
        int base = c * EPB;
        int end = base + EPB < E ? base + EPB : E;
        for (int i = base + threadIdx.x; i < end; i += 256) {
            int v = es[i], f = ed[i];
            if (v >= vLo && v < vHi) atomicAdd(&cntV[v], 1);
            if (f >= fLo && f < fHi) atomicAdd(&cntF[f], 1);
        }
    }
}

__global__ __launch_bounds__(256) void fill_part(
    const int* __restrict__ es, const int* __restrict__ ed,
    const int* __restrict__ rsF, const int* __restrict__ rsV,
    int* __restrict__ cntF, int* __restrict__ cntV,
    int* __restrict__ elF, int* __restrict__ elV,
    int E, int CH, int vChunk, int fChunk)
{
    int part = blockIdx.x & 7;
    int vLo = part * vChunk, vHi = vLo + vChunk;
    int fLo = part * fChunk, fHi = fLo + fChunk;
    for (int c = blockIdx.x >> 3; c < CH; c += NPB) {
        int base = c * EPB;
        int end = base + EPB < E ? base + EPB : E;
        for (int i = base + threadIdx.x; i < end; i += 256) {
            int v = es[i], f = ed[i];
            if (f >= fLo && f < fHi) { int p = rsF[f] + atomicSub(&cntF[f], 1) - 1; elF[p] = v; }
            if (v >= vLo && v < vHi) { int p = rsV[v] + atomicSub(&cntV[v], 1) - 1; elV[p] = f; }
        }
    }
}

// -------------------------------------------------------------------------
// Dual-array exclusive scans (F and V in one launch each).
// -------------------------------------------------------------------------
__device__ __forceinline__ void scan1_body(
    const int* __restrict__ cnt, int* __restrict__ rs, int* __restrict__ bsum,
    int N, int b)
{
    __shared__ int sd[256];
    int t = threadIdx.x;
    int b0 = b * 1024;
    int v[4]; int s = 0;
#pragma unroll
    for (int j = 0; j < 4; j++) { int i = b0 + t * 4 + j; v[j] = (i < N) ? cnt[i] : 0; s += v[j]; }
    sd[t] = s; __syncthreads();
    for (int off = 1; off < 256; off <<= 1) {
        int x = (t >= off) ? sd[t - off] : 0;
        __syncthreads();
        sd[t] += x;
        __syncthreads();
    }
    int excl = sd[t] - s;
    if (t == 255) bsum[b] = sd[255];
    int run = excl;
#pragma unroll
    for (int j = 0; j < 4; j++) { int i = b0 + t * 4 + j; if (i < N) rs[i] = run; run += v[j]; }
}

__global__ __launch_bounds__(256) void scan1_dual(
    const int* __restrict__ cntF, int* __restrict__ rsF, int* __restrict__ bsum,
    int NF, int NV, int NBf)
{
    if ((int)blockIdx.x < NBf)
        scan1_body(cntF, rsF, bsum, NF, blockIdx.x);
    else
        scan1_body(cntF + NF, rsF + NF + 1, bsum + 512, NV, blockIdx.x - NBf);
}

__device__ __forceinline__ void scan2_body(int* __restrict__ bsum, int NB)
{
    __shared__ int sd[256];
    int t = threadIdx.x;
    int s = (t < NB) ? bsum[t] : 0;
    sd[t] = s; __syncthreads();
    for (int off = 1; off < 256; off <<= 1) {
        int x = (t >= off) ? sd[t - off] : 0;
        __syncthreads();
        sd[t] += x;
        __syncthreads();
    }
    if (t < NB) bsum[t] = sd[t] - s;
}

__global__ __launch_bounds__(256) void scan2_dual(int* __restrict__ bsum, int NBf, int NBv)
{
    if (blockIdx.x == 0) scan2_body(bsum, NBf);
    else                 scan2_body(bsum + 512, NBv);
}

__global__ __launch_bounds__(256) void scan3_dual(
    int* __restrict__ rsF, const int* __restrict__ bsum,
    int NF, int NV, int E, int GBf)
{
    if ((int)blockIdx.x < GBf) {
        int i = blockIdx.x * 256 + threadIdx.x;
        if (i < NF) rsF[i] += bsum[i >> 10];
        else if (i == NF) rsF[NF] = E;
    } else {
        int i = (blockIdx.x - GBf) * 256 + threadIdx.x;
        int* rsV = rsF + NF + 1;
        if (i < NV) rsV[i] += bsum[512 + (i >> 10)];
        else if (i == NV) rsV[NV] = E;
    }
}

// -------------------------------------------------------------------------
// CSR aggregation (one wave per row, 8x/4x unrolled gathers):
//   OWN[w] <- bf16( sum_{o in adj(w)} relu(OWN[w] + OTH[o] + bias) )
// -------------------------------------------------------------------------
__global__ __launch_bounds__(256) void aggregate_k(
    u16* __restrict__ OWN, const u16* __restrict__ OTH,
    const int* __restrict__ rs, const int* __restrict__ el,
    const float* __restrict__ bias, int N)
{
    int row = blockIdx.x * 4 + (threadIdx.x >> 6);
    if (row >= N) return;
    int lane = threadIdx.x & 63;
    int start = rs[row], end = rs[row + 1];
    ushort2 h = *(const ushort2*)&OWN[(size_t)row * 128 + lane * 2];
    float2 bv = *(const float2*)&bias[lane * 2];
    float c0 = bf2f(h.x) + bv.x;
    float c1 = bf2f(h.y) + bv.y;
    float a0 = 0.f, a1 = 0.f;
    for (int p0 = start; p0 < end; p0 += 64) {
        int n = end - p0; if (n > 64) n = 64;
        int myidx = (lane < n) ? el[p0 + lane] : 0;
        int j = 0;
        for (; j + 8 <= n; j += 8) {
            ushort2 b0 = *(const ushort2*)&OTH[(size_t)__shfl(myidx, j)     * 128 + lane * 2];
            ushort2 b1 = *(const ushort2*)&OTH[(size_t)__shfl(myidx, j + 1) * 128 + lane * 2];
            ushort2 b2 = *(const ushort2*)&OTH[(size_t)__shfl(myidx, j + 2) * 128 + lane * 2];
            ushort2 b3 = *(const ushort2*)&OTH[(size_t)__shfl(myidx, j + 3) * 128 + lane * 2];
            ushort2 b4 = *(const ushort2*)&OTH[(size_t)__shfl(myidx, j + 4) * 128 + lane * 2];
            ushort2 b5 = *(const ushort2*)&OTH[(size_t)__shfl(myidx, j + 5) * 128 + lane * 2];
            ushort2 b6 = *(const ushort2*)&OTH[(size_t)__shfl(myidx, j + 6) * 128 + lane * 2];
            ushort2 b7 = *(const ushort2*)&OTH[(size_t)__shfl(myidx, j + 7) * 128 + lane * 2];
            a0 += fmaxf(c0 + bf2f(b0.x), 0.f) + fmaxf(c0 + bf2f(b1.x), 0.f)
                + fmaxf(c0 + bf2f(b2.x), 0.f) + fmaxf(c0 + bf2f(b3.x), 0.f)
                + fmaxf(c0 + bf2f(b4.x), 0.f) + fmaxf(c0 + bf2f(b5.x), 0.f)
                + fmaxf(c0 + bf2f(b6.x), 0.f) + fmaxf(c0 + bf2f(b7.x), 0.f);
            a1 += fmaxf(c1 + bf2f(b0.y), 0.f) + fmaxf(c1 + bf2f(b1.y), 0.f)
                + fmaxf(c1 + bf2f(b2.y), 0.f) + fmaxf(c1 + bf2f(b3.y), 0.f)
                + fmaxf(c1 + bf2f(b4.y), 0.f) + fmaxf(c1 + bf2f(b5.y), 0.f)
                + fmaxf(c1 + bf2f(b6.y), 0.f) + fmaxf(c1 + bf2f(b7.y), 0.f);
        }
        for (; j + 4 <= n; j += 4) {
            ushort2 b0 = *(const ushort2*)&OTH[(size_t)__shfl(myidx, j)     * 128 + lane * 2];
            ushort2 b1 = *(const ushort2*)&OTH[(size_t)__shfl(myidx, j + 1) * 128 + lane * 2];
            ushort2 b2 = *(const ushort2*)&OTH[(size_t)__shfl(myidx, j + 2) * 128 + lane * 2];
            ushort2 b3 = *(const ushort2*)&OTH[(size_t)__shfl(myidx, j + 3) * 128 + lane * 2];
            a0 += fmaxf(c0 + bf2f(b0.x), 0.f) + fmaxf(c0 + bf2f(b1.x), 0.f)
                + fmaxf(c0 + bf2f(b2.x), 0.f) + fmaxf(c0 + bf2f(b3.x), 0.f);
            a1 += fmaxf(c1 + bf2f(b0.y), 0.f) + fmaxf(c1 + bf2f(b1.y), 0.f)
                + fmaxf(c1 + bf2f(b2.y), 0.f) + fmaxf(c1 + bf2f(b3.y), 0.f);
        }
        for (; j < n; j++) {
            ushort2 b = *(const ushort2*)&OTH[(size_t)__shfl(myidx, j) * 128 + lane * 2];
            a0 += fmaxf(c0 + bf2f(b.x), 0.f);
            a1 += fmaxf(c1 + bf2f(b.y), 0.f);
        }
    }
    ushort2 r; r.x = f2bf(a0); r.y = f2bf(a1);
    *(ushort2*)&OWN[(size_t)row * 128 + lane * 2] = r;
}

// -------------------------------------------------------------------------
// GEMM building blocks.
// -------------------------------------------------------------------------
__device__ __forceinline__ void stage_Xf(const float* __restrict__ X, int r0, int N,
                                         u16* __restrict__ Xs, int tid)
{
#pragma unroll
    for (int j = 0; j < 8; j++) {
        int q = j * 256 + tid;
        int row = q >> 5;
        int col = (q & 31) * 4;
        float4 v = make_float4(0.f, 0.f, 0.f, 0.f);
        int gr = r0 + row;
        if (gr < N) v = *(const float4*)&X[(size_t)gr * 128 + col];
        ushort4 h;
        h.x = f2bf(v.x); h.y = f2bf(v.y); h.z = f2bf(v.z); h.w = f2bf(v.w);
        *(ushort4*)&Xs[row * 136 + col] = h;
    }
}
__device__ __forceinline__ void stage_Xb(const u16* __restrict__ X, int r0, int N,
                                         u16* __restrict__ Xs, int tid)
{
#pragma unroll
    for (int j = 0; j < 4; j++) {
        int q = j * 256 + tid;
        int row = q >> 4;
        int col = (q & 15) * 8;
        uint4 v = make_uint4(0, 0, 0, 0);
        int gr = r0 + row;
        if (gr < N) v = *(const uint4*)&X[(size_t)gr * 128 + col];
        *(uint4*)&Xs[row * 136 + col] = v;
    }
}
__device__ __forceinline__ void stage_W(const u16* __restrict__ W, u16* __restrict__ Ws, int tid)
{
#pragma unroll
    for (int j = 0; j < 8; j++) {
        int q = j * 256 + tid;
        int c = q >> 4;
        int k = (q & 15) * 8;
        *(uint4*)&Ws[c * 136 + k] = *(const uint4*)&W[c * 128 + k];
    }
}
__device__ __forceinline__ void mfma8(const u16* __restrict__ Xs, const u16* __restrict__ Ws,
                                      int lane, int wv, f32x4* acc)
{
#pragma unroll
    for (int ks = 0; ks < 4; ks++) {
        bf16x8 a = *(const bf16x8*)&Xs[(wv * 16 + (lane & 15)) * 136 + ks * 32 + (lane >> 4) * 8];
#pragma unroll
        for (int ct = 0; ct < 8; ct++) {
            bf16x8 b = *(const bf16x8*)&Ws[(ct * 16 + (lane & 15)) * 136 + ks * 32 + (lane >> 4) * 8];
            acc[ct] = __builtin_amdgcn_mfma_f32_16x16x32_bf16(a, b, acc[ct], 0, 0, 0);
        }
    }
}

// -------------------------------------------------------------------------
// proj3: blocks [0,GBf): Fh_m = F@W0 -> BUFA, Fh2 = F@W3 -> BUFC (dual);
//        blocks [GBf,..): Vh_m = V@W1 -> BUFB.   All bf16 out.
// -------------------------------------------------------------------------
__global__ __launch_bounds__(256) void proj3_k(
    const float* __restrict__ F, const float* __restrict__ V,
    const u16* __restrict__ W0, const u16* __restrict__ W3, const u16* __restrict__ W1,
    u16* __restrict__ BUFA, u16* __restrict__ BUFC, u16* __restrict__ BUFB,
    int NF, int NV, int GBf)
{
    __shared__ __align__(16) u16 Xs[64 * 136];
    __shared__ __align__(16) u16 Ws[128 * 136];
    const int tid = threadIdx.x, lane = tid & 63, wv = tid >> 6;
    if ((int)blockIdx.x < GBf) {
        const int r0 = blockIdx.x * 64;
        f32x4 acc1[8], acc2[8];
#pragma unroll
        for (int i = 0; i < 8; i++) { acc1[i] = (f32x4)0.f; acc2[i] = (f32x4)0.f; }
        stage_Xf(F, r0, NF, Xs, tid);
        stage_W(W0, Ws, tid);
        __syncthreads();
        mfma8(Xs, Ws, lane, wv, acc1);
        __syncthreads();
        stage_W(W3, Ws, tid);
        __syncthreads();
        mfma8(Xs, Ws, lane, wv, acc2);
#pragma unroll
        for (int ct = 0; ct < 8; ct++) {
            int col = ct * 16 + (lane & 15);
#pragma unroll
            for (int r = 0; r < 4; r++) {
                int gr = r0 + wv * 16 + (lane >> 4) * 4 + r;
                if (gr < NF) {
                    BUFA[(size_t)gr * 128 + col] = f2bf(acc1[ct][r]);
                    BUFC[(size_t)gr * 128 + col] = f2bf(acc2[ct][r]);
                }
            }
        }
    } else {
        const int r0 = (blockIdx.x - GBf) * 64;
        f32x4 acc[8];
#pragma unroll
        for (int i = 0; i < 8; i++) acc[i] = (f32x4)0.f;
        stage_Xf(V, r0, NV, Xs, tid);
        stage_W(W1, Ws, tid);
        __syncthreads();
        mfma8(Xs, Ws, lane, wv, acc);
#pragma unroll
        for (int ct = 0; ct < 8; ct++) {
            int col = ct * 16 + (lane & 15);
#pragma unroll
            for (int r = 0; r < 4; r++) {
                int gr = r0 + wv * 16 + (lane >> 4) * 4 + r;
                if (gr < NV) BUFB[(size_t)gr * 128 + col] = f2bf(acc[ct][r]);
            }
        }
    }
}

// -------------------------------------------------------------------------
// mixF: blocks [0,GBf): F_new = relu(F@W4 + AGG@W5 + bc) -> out_f (f32);
//       optionally gate[row] = F_new . Wg + bg (fused, last layer).
//       blocks [GBf,..): Vh2 = V@W2 -> BUFB (bf16).
// -------------------------------------------------------------------------
template <bool GATE>
__global__ __launch_bounds__(256) void mixF_k(
    const float* __restrict__ Fin, const u16* __restrict__ AGG,
    const u16* __restrict__ W4, const u16* __restrict__ W5,
    const float* __restrict__ bc, float* __restrict__ out_f,
    const float* __restrict__ Vin, const u16* __restrict__ W2,
    u16* __restrict__ BUFB,
    const float* __restrict__ Wg, const float* __restrict__ bg,
    float* __restrict__ gate, int NF, int NV, int GBf)
{
    __shared__ __align__(16) u16 Xs[64 * 136];
    __shared__ __align__(16) u16 Ws[128 * 136];
    const int tid = threadIdx.x, lane = tid & 63, wv = tid >> 6;
    if ((int)blockIdx.x < GBf) {
        const int r0 = blockIdx.x * 64;
        f32x4 acc[8];
#pragma unroll
        for (int i = 0; i < 8; i++) acc[i] = (f32x4)0.f;
        stage_Xf(Fin, r0, NF, Xs, tid);
        stage_W(W4, Ws, tid);
        __syncthreads();
        mfma8(Xs, Ws, lane, wv, acc);
        __syncthreads();
        stage_Xb(AGG, r0, NF, Xs, tid);
        stage_W(W5, Ws, tid);
        __syncthreads();
        mfma8(Xs, Ws, lane, wv, acc);
        float gp[4] = {0.f, 0.f, 0.f, 0.f};
#pragma unroll
        for (int ct = 0; ct < 8; ct++) {
            int col = ct * 16 + (lane & 15);
            float bv = bc[col];
            float wgv = GATE ? Wg[col] : 0.f;
#pragma unroll
            for (int r = 0; r < 4; r++) {
                int gr = r0 + wv * 16 + (lane >> 4) * 4 + r;
                if (gr < NF) {
                    float v = fmaxf(acc[ct][r] + bv, 0.f);
                    out_f[(size_t)gr * 128 + col] = v;
                    if (GATE) gp[r] += v * wgv;
                }
            }
        }
        if (GATE) {
#pragma unroll
            for (int r = 0; r < 4; r++) {
                gp[r] += __shfl_xor(gp[r], 1);
                gp[r] += __shfl_xor(gp[r], 2);
                gp[r] += __shfl_xor(gp[r], 4);
                gp[r] += __shfl_xor(gp[r], 8);
            }
            if ((lane & 15) == 0) {
                float b0 = bg[0];
#pragma unroll
                for (int r = 0; r < 4; r++) {
                    int gr = r0 + wv * 16 + (lane >> 4) * 4 + r;
                    if (gr < NF) gate[gr] = gp[r] + b0;
                }
            }
        }
    } else {
        const int r0 = (blockIdx.x - GBf) * 64;
        f32x4 acc[8];
#pragma unroll
        for (int i = 0; i < 8; i++) acc[i] = (f32x4)0.f;
        stage_Xf(Vin, r0, NV, Xs, tid);
        stage_W(W2, Ws, tid);
        __syncthreads();
        mfma8(Xs, Ws, lane, wv, acc);
#pragma unroll
        for (int ct = 0; ct < 8; ct++) {
            int col = ct * 16 + (lane & 15);
#pragma unroll
            for (int r = 0; r < 4; r++) {
                int gr = r0 + wv * 16 + (lane >> 4) * 4 + r;
                if (gr < NV) BUFB[(size_t)gr * 128 + col] = f2bf(acc[ct][r]);
            }
        }
    }
}

// -------------------------------------------------------------------------
// combineV: V_new = V + relu(V@W6 + AGG@W7 + bc) -> out_v (f32)
// -------------------------------------------------------------------------
__global__ __launch_bounds__(256) void combineV_k(
    const float* __restrict__ Vin, const u16* __restrict__ AGG,
    const u16* __restrict__ W6, const u16* __restrict__ W7,
    const float* __restrict__ bc, float* __restrict__ out_v, int NV)
{
    __shared__ __align__(16) u16 Xs[64 * 136];
    __shared__ __align__(16) u16 Ws[128 * 136];
    const int tid = threadIdx.x, lane = tid & 63, wv = tid >> 6;
    const int r0 = blockIdx.x * 64;
    f32x4 acc[8];
#pragma unroll
    for (int i = 0; i < 8; i++) acc[i] = (f32x4)0.f;
    stage_Xf(Vin, r0, NV, Xs, tid);
    stage_W(W6, Ws, tid);
    __syncthreads();
    mfma8(Xs, Ws, lane, wv, acc);
    __syncthreads();
    stage_Xb(AGG, r0, NV, Xs, tid);
    stage_W(W7, Ws, tid);
    __syncthreads();
    mfma8(Xs, Ws, lane, wv, acc);
#pragma unroll
    for (int ct = 0; ct < 8; ct++) {
        int col = ct * 16 + (lane & 15);
        float bv = bc[col];
#pragma unroll
        for (int r = 0; r < 4; r++) {
            int gr = r0 + wv * 16 + (lane >> 4) * 4 + r;
            if (gr < NV) {
                float v = fmaxf(acc[ct][r] + bv, 0.f) + Vin[(size_t)gr * 128 + col];
                out_v[(size_t)gr * 128 + col] = v;
            }
        }
    }
}

// -------------------------------------------------------------------------
// gstats: per-group softmax over gate, normalized in place (gate -> attn);
// also zeros this group's g_att row (pre-wsum). dn[g]=denominator.
// -------------------------------------------------------------------------
__global__ __launch_bounds__(256) void gstats_k(
    float* __restrict__ gate, const int* __restrict__ batch,
    float* __restrict__ dn, float* __restrict__ g_att, int NF)
{
    int g = blockIdx.x, tid = threadIdx.x;
    if (tid < 128) g_att[(size_t)g * 128 + tid] = 0.f;
    int lo = 0, hi = NF;
    while (lo < hi) { int mid = (lo + hi) >> 1; if (batch[mid] < g) lo = mid + 1; else hi = mid; }
    int start = lo;
    lo = start; hi = NF;
    while (lo < hi) { int mid = (lo + hi) >> 1; if (batch[mid] < g + 1) lo = mid + 1; else hi = mid; }
    int end = lo;

    __shared__ float red[256];
    float m = -3.4e38f;
    for (int i = start + tid; i < end; i += 256) m = fmaxf(m, gate[i]);
    red[tid] = m; __syncthreads();
    for (int s = 128; s; s >>= 1) { if (tid < s) red[tid] = fmaxf(red[tid], red[tid + s]); __syncthreads(); }
    float mval = red[0]; __syncthreads();
    float s = 0.f;
    for (int i = start + tid; i < end; i += 256) {
        float e = __expf(gate[i] - mval);
        gate[i] = e;
        s += e;
    }
    red[tid] = s; __syncthreads();
    for (int t = 128; t; t >>= 1) { if (tid < t) red[tid] += red[tid + t]; __syncthreads(); }
    float denom = red[0];
    if (tid == 0) dn[g] = denom;
    float rdn = (denom > 0.f) ? 1.f / denom : 0.f;
    for (int i = start + tid; i < end; i += 256) gate[i] *= rdn;
}

// -------------------------------------------------------------------------
// wsum: g_att[g] += sum_i attn[i] * F[i]  over 32-row chunks (sorted batch).
// -------------------------------------------------------------------------
__global__ __launch_bounds__(128) void wsum_k(
    const float* __restrict__ attn, const float* __restrict__ F,
    const int* __restrict__ batch, float* __restrict__ g_att, int NF)
{
    int tid = threadIdx.x;
    int i0 = blockIdx.x * 32;
    if (i0 >= NF) return;
    int iend = i0 + 32; if (iend > NF) iend = NF;
    int curg = batch[i0];
    float acc = 0.f;
    for (int i = i0; i < iend; i++) {
        int g = batch[i];
        if (g != curg) {
            atomicAdd(&g_att[(size_t)curg * 128 + tid], acc);
            acc = 0.f; curg = g;
        }
        acc += attn[i] * F[(size_t)i * 128 + tid];
    }
    atomicAdd(&g_att[(size_t)curg * 128 + tid], acc);
}

// -------------------------------------------------------------------------
// gfinal: t = (nonempty? g_att@Wt + bt : 0); out = relu(t@Wl_top + bl)
// -------------------------------------------------------------------------
__global__ __launch_bounds__(128) void gfinal_k(
    const float* __restrict__ g_att, const float* __restrict__ dn,
    const float* __restrict__ Wt, const float* __restrict__ bt,
    const float* __restrict__ Wl, const float* __restrict__ bl,
    float* __restrict__ out_g)
{
    int g = blockIdx.x, tid = threadIdx.x;
    __shared__ float ga[128], tt[128];
    ga[tid] = g_att[(size_t)g * 128 + tid];
    __syncthreads();
    float t = 0.f;
    for (int k = 0; k < 128; k++) t += ga[k] * Wt[k * 128 + tid];
    bool nonempty = dn[g] > 0.f;
    t = nonempty ? t + bt[tid] : 0.f;
    tt[tid] = t; __syncthreads();
    float o = bl[tid];
    for (int k = 0; k < 128; k++) o += tt[k] * Wl[k * 128 + tid];
    out_g[(size_t)g * 128 + tid] = fmaxf(o, 0.f);
}

// -------------------------------------------------------------------------
extern "C" void kernel_launch(void* const* d_in, const int* in_sizes, int n_in,
                              void* d_out, int out_size, void* d_ws, size_t ws_size,
                              hipStream_t stream)
{
    const int D = 128;
    const int NV = in_sizes[0] / D;
    const int NF = in_sizes[1] / D;
    const int E  = in_sizes[2] / 2;
    const int G  = out_size / D - NV - NF;

    const float* vars_in = (const float*)d_in[0];
    const float* facs_in = (const float*)d_in[1];
    const int*   eidx    = (const int*)d_in[2];
    const int*   e_src   = eidx;        // variable index per edge
    const int*   e_dst   = eidx + E;    // factor index per edge
    const int*   batch   = (const int*)d_in[4];
    const float* Wm_vf = (const float*)d_in[5],  *bm_vf = (const float*)d_in[6];
    const float* Wc_vf = (const float*)d_in[7],  *bc_vf = (const float*)d_in[8];
    const float* Wm_fv = (const float*)d_in[9],  *bm_fv = (const float*)d_in[10];
    const float* Wc_fv = (const float*)d_in[11], *bc_fv = (const float*)d_in[12];
    const float* Wg  = (const float*)d_in[13], *bg = (const float*)d_in[14];
    const float* Wtr = (const float*)d_in[15], *bt = (const float*)d_in[16];
    const float* Wl  = (const float*)d_in[17], *bl = (const float*)d_in[18];

    // workspace (~86 MB peak; 103.4 MB known-safe)
    char* ws = (char*)d_ws;
    size_t off = 0;
    u16* WB   = (u16*)ws;            off = 1u << 20;
    u16* BUFA = (u16*)(ws + off);    off += (size_t)NF * 256;
    u16* BUFB = (u16*)(ws + off);    off += (size_t)NV * 256;
    u16* BUFC = (u16*)(ws + off);    off += (size_t)NF * 256;
    int* rsF  = (int*)(ws + off);    off += (size_t)(NF + 1) * 4;   // rsV contiguous after
    off += (size_t)(NV + 1) * 4;
    int* cntF = (int*)(ws + off);    off += (size_t)NF * 4;         // cntV contiguous after
    int* cntV = (int*)(ws + off);    off += (size_t)NV * 4;
    int* elF  = (int*)(ws + off);    off += (size_t)E * 4;
    int* elV  = (int*)(ws + off);    off += (size_t)E * 4;
    int* bsum = (int*)(ws + off);    off += 4096;
    float* dn    = (float*)(ws + off); off += (size_t)G * 4;
    float* g_att = (float*)(ws + off); off += (size_t)G * 512;
    float* gate  = (float*)(ws + off); off += (size_t)NF * 4;

    int* rsV = rsF + NF + 1;

    float* out_v = (float*)d_out;
    float* out_f = out_v + (size_t)NV * D;
    float* out_g = out_f + (size_t)NF * D;

    // setup: weight transpose + zero cnt arrays (fused)
    const int cntN = NF + NV;
    setup_k<<<(16 * 16384 + cntN + 255) / 256, 256, 0, stream>>>(
        Wm_vf, Wc_vf, Wm_fv, Wc_fv, WB, cntF, cntN);

    // ---- CSR build (both directions), persistent XCD-pinned blocks ----
    const int vChunk = (NV + 7) / 8, fChunk = (NF + 7) / 8;
    const int CH = (E + EPB - 1) / EPB;
    hist_part<<<8 * NPB, 256, 0, stream>>>(e_src, e_dst, cntV, cntF, E, CH, vChunk, fChunk);
    const int NBf = (NF + 1023) / 1024, NBv = (NV + 1023) / 1024;
    scan1_dual<<<NBf + NBv, 256, 0, stream>>>(cntF, rsF, bsum, NF, NV, NBf);
    scan2_dual<<<2, 256, 0, stream>>>(bsum, NBf, NBv);
    const int GB3f = (NF + 256) / 256, GB3v = (NV + 256) / 256;
    scan3_dual<<<GB3f + GB3v, 256, 0, stream>>>(rsF, bsum, NF, NV, E, GB3f);
    fill_part<<<8 * NPB, 256, 0, stream>>>(e_src, e_dst, rsF, rsV, cntF, cntV, elF, elV, E, CH, vChunk, fChunk);

    const int GBv = (NV + 63) / 64;
    const int GBf = (NF + 63) / 64;
    const int GAf = (NF + 3) / 4;
    const int GAv = (NV + 3) / 4;

    for (int l = 0; l < 2; l++) {
        u16* wb = WB + l * 8 * 16384;
        const float* Fin = l ? out_f : facs_in;
        const float* Vin = l ? out_v : vars_in;
        // projections: Fh_m -> BUFA, Fh2 -> BUFC, Vh_m -> BUFB
        proj3_k<<<GBf + GBv, 256, 0, stream>>>(
            Fin, Vin, wb + 0 * 16384, wb + 3 * 16384, wb + 1 * 16384,
            BUFA, BUFC, BUFB, NF, NV, GBf);
        // AGG_F = segsum relu(Fh_m[dst] + Vh_m[src] + bm_vf)  (in place, BUFA)
        aggregate_k<<<GAf, 256, 0, stream>>>(BUFA, BUFB, rsF, elF, bm_vf + l * D, NF);
        // F_new -> out_f (+ fused gate on last layer); Vh2 -> BUFB
        if (l == 0)
            mixF_k<false><<<GBf + GBv, 256, 0, stream>>>(
                Fin, BUFA, wb + 4 * 16384, wb + 5 * 16384, bc_vf + l * D, out_f,
                Vin, wb + 2 * 16384, BUFB, nullptr, nullptr, nullptr, NF, NV, GBf);
        else
            mixF_k<true><<<GBf + GBv, 256, 0, stream>>>(
                Fin, BUFA, wb + 4 * 16384, wb + 5 * 16384, bc_vf + l * D, out_f,
                Vin, wb + 2 * 16384, BUFB, Wg, bg, gate, NF, NV, GBf);
        // AGG_V = segsum relu(Vh2[src] + Fh2[dst] + bm_fv)  (in place, BUFB)
        aggregate_k<<<GAv, 256, 0, stream>>>(BUFB, BUFC, rsV, elV, bm_fv + l * D, NV);
        // V_new = V + relu(...) -> out_v
        combineV_k<<<GBv, 256, 0, stream>>>(
            Vin, BUFB, wb + 6 * 16384, wb + 7 * 16384, bc_fv + l * D, out_v, NV);
    }

    // ---- global node ----
    gstats_k<<<G, 256, 0, stream>>>(gate, batch, dn, g_att, NF);
    wsum_k<<<(NF + 31) / 32, 128, 0, stream>>>(gate, out_f, batch, g_att, NF);
    gfinal_k<<<G, 128, 0, stream>>>(g_att, dn, Wtr, bt, Wl, bl, out_g);
}